// Round 1
// baseline (244.502 us; speedup 1.0000x reference)
//
#include <hip/hip_runtime.h>
#include <hip/hip_bf16.h>

#define B_SZ   2
#define H_SZ   48
#define W_SZ   48
#define L_SZ   2304          // H*W
#define CIN    768           // C_INNER
#define KG     4
#define DI     192           // D_IN (channels per direction)
#define NS     16            // N_STATE
#define RR     12            // R_RANK
#define XD     44            // RR + 2*NS
#define MTOK   4608          // B*L
#define CL     32            // scan chunk length
#define NC     72            // L / CL

typedef __attribute__((ext_vector_type(8))) short short8;
typedef __attribute__((ext_vector_type(4))) float f32x4;

__device__ inline ushort f2b(float f) {
    uint u = __builtin_bit_cast(uint, f);
    u = (u + 0x7FFF + ((u >> 16) & 1)) >> 16;   // RNE to bf16
    return (ushort)u;
}
__device__ inline float b2f(ushort b) {
    uint u = ((uint)b) << 16;
    return __builtin_bit_cast(float, u);
}
__device__ inline short8 f2b8(float4 a, float4 b) {
    short8 r;
    r[0] = (short)f2b(a.x); r[1] = (short)f2b(a.y);
    r[2] = (short)f2b(a.z); r[3] = (short)f2b(a.w);
    r[4] = (short)f2b(b.x); r[5] = (short)f2b(b.y);
    r[6] = (short)f2b(b.z); r[7] = (short)f2b(b.w);
    return r;
}

// ---------------------------------------------------------------------------
// MFMA GEMM, TN=64 column tiles:  C[M,N] = A[M,K] * Bw[N,K]^T
// (used for the in-proj GEMM only now)
// ---------------------------------------------------------------------------
template<int TM, bool ABF, bool CBF>
__global__ __launch_bounds__(256) void gemm_tn64(
        const void* __restrict__ Av, const float* __restrict__ Bw,
        void* __restrict__ Cv, int M, int N, int K) {
    __shared__ ushort As[TM][40];
    __shared__ ushort Bs[64][40];
    const int tid  = threadIdx.x;
    const int lane = tid & 63;
    const int wave = tid >> 6;
    constexpr int MF = TM / 64;
    const int wrow = wave * (MF * 16);
    const int bm = blockIdx.y * TM, bn = blockIdx.x * 64;
    const int frow = lane & 15;
    const int fk   = (lane >> 4) * 8;
    const int orow = (lane >> 4) * 4;

    f32x4 acc[MF][4] = {};

    for (int k0 = 0; k0 < K; k0 += 32) {
        short8 aval[MF];
#pragma unroll
        for (int i = 0; i < MF; ++i) {
            int idx = tid + i * 256;
            int row = idx >> 2, q = idx & 3;
            if (ABF) {
                aval[i] = *(const short8*)&((const ushort*)Av)[(size_t)(bm + row) * K + k0 + q * 8];
            } else {
                const float* ap = &((const float*)Av)[(size_t)(bm + row) * K + k0 + q * 8];
                aval[i] = f2b8(*(const float4*)ap, *(const float4*)(ap + 4));
            }
        }
        const float* bp = &Bw[(size_t)(bn + (tid >> 2)) * K + k0 + (tid & 3) * 8];
        short8 bval = f2b8(*(const float4*)bp, *(const float4*)(bp + 4));

        __syncthreads();
#pragma unroll
        for (int i = 0; i < MF; ++i) {
            int idx = tid + i * 256;
            *(short8*)&As[idx >> 2][(idx & 3) * 8] = aval[i];
        }
        *(short8*)&Bs[tid >> 2][(tid & 3) * 8] = bval;
        __syncthreads();

        short8 af[MF], bf[4];
#pragma unroll
        for (int mi = 0; mi < MF; ++mi)
            af[mi] = *(const short8*)&As[wrow + mi * 16 + frow][fk];
#pragma unroll
        for (int ni = 0; ni < 4; ++ni)
            bf[ni] = *(const short8*)&Bs[ni * 16 + frow][fk];
#pragma unroll
        for (int mi = 0; mi < MF; ++mi)
#pragma unroll
            for (int ni = 0; ni < 4; ++ni)
                acc[mi][ni] = __builtin_amdgcn_mfma_f32_16x16x32_bf16(
                                  af[mi], bf[ni], acc[mi][ni], 0, 0, 0);
    }

#pragma unroll
    for (int mi = 0; mi < MF; ++mi) {
        int rbase = bm + wrow + mi * 16 + orow;
#pragma unroll
        for (int ni = 0; ni < 4; ++ni) {
            int col = bn + ni * 16 + frow;
#pragma unroll
            for (int r = 0; r < 4; ++r) {
                if (CBF)
                    ((ushort*)Cv)[(size_t)(rbase + r) * N + col] = f2b(acc[mi][ni][r]);
                else
                    ((float*)Cv)[(size_t)(rbase + r) * N + col] = acc[mi][ni][r];
            }
        }
    }
}

// ---------------------------------------------------------------------------
// Depthwise 3x3 conv (SAME) + bias + SiLU on bf16 NHWC input; scatter into
// the four scan orders xsb[b][k][l'][d] (bf16).
// ---------------------------------------------------------------------------
__global__ __launch_bounds__(256) void conv_silu_scatter(
        const ushort* __restrict__ xzb, const float* __restrict__ cw,
        const float* __restrict__ cb, ushort* __restrict__ xsb) {
    int idx = blockIdx.x * 256 + threadIdx.x;
    int c = idx % CIN;
    int rest = idx / CIN;
    int w = rest % W_SZ; rest /= W_SZ;
    int h = rest % H_SZ;
    int b = rest / H_SZ;

    float acc = cb[c];
#pragma unroll
    for (int dh = -1; dh <= 1; ++dh) {
        int hh = h + dh;
        if (hh < 0 || hh >= H_SZ) continue;
#pragma unroll
        for (int dw = -1; dw <= 1; ++dw) {
            int ww = w + dw;
            if (ww < 0 || ww >= W_SZ) continue;
            acc += b2f(xzb[(size_t)((b * H_SZ + hh) * W_SZ + ww) * CIN + c])
                 * cw[c * 9 + (dh + 1) * 3 + (dw + 1)];
        }
    }
    float s = acc / (1.f + __expf(-acc));   // SiLU

    int k = c / DI, d = c % DI;
    int lrow = h * W_SZ + w;
    int lcol = w * H_SZ + h;
    int l;
    if      (k == 0) l = lrow;
    else if (k == 1) l = lcol;
    else if (k == 2) l = L_SZ - 1 - lrow;
    else             l = L_SZ - 1 - lcol;
    xsb[(size_t)((b * KG + k) * L_SZ + l) * DI + d] = f2b(s);
}

// ---------------------------------------------------------------------------
// FUSED: MFMA x-projection + dt-projection + scan pass A.
// Block = 64 tokens of one (b,k) = exactly 2 scan chunks of CL=32.
// B-state values (acc1 cols RR..RR+NS) are kept in LDS (bshL) for the scan
// phase; dts is re-read from global (written by this block; barrier drains
// vmcnt, L2 serves the re-read on the same CU).
// ---------------------------------------------------------------------------
__global__ __launch_bounds__(768) void xproj_dt_scanA(
        const ushort* __restrict__ xsb, const float* __restrict__ xpw,
        const float* __restrict__ dtw, const float* __restrict__ dtb,
        const float* __restrict__ A_logs,
        float* __restrict__ xdbl, ushort* __restrict__ dts_b,
        float* __restrict__ Ebuf, float* __restrict__ Sbuf) {
    __shared__ ushort Ws[48][200];
    __shared__ ushort Wd[192][40];
    __shared__ ushort dsh[64][40];
    __shared__ float  bshL[64][NS];

    const int tid  = threadIdx.x;
    const int lane = tid & 63;
    const int wave = tid >> 6;        // 0..11
    const int bm = blockIdx.x * 64;
    const int bk = blockIdx.y;
    const int k  = bk & 3;
    const int frow = lane & 15;
    const int fk   = (lane >> 4) * 8;
    const int orow = (lane >> 4) * 4;
    const int rg = wave & 3;
    const int cg = wave >> 2;

#pragma unroll
    for (int i = 0; i < 3; ++i) {
        int idx = tid + i * 768;
        int row = idx / 48, g = idx % 48;
        ushort4 u = {0, 0, 0, 0};
        if (row < XD) {
            float4 v = *(const float4*)&xpw[((size_t)(k * XD) + row) * 192 + g * 4];
            u.x = f2b(v.x); u.y = f2b(v.y); u.z = f2b(v.z); u.w = f2b(v.w);
        }
        *(ushort4*)&Ws[row][g * 4] = u;
    }
#pragma unroll
    for (int i = 0; i < 2; ++i) {
        int idx = tid + i * 768;
        if (idx < 960) {
            float4 z = {0.f, 0.f, 0.f, 0.f};
            *(float4*)&Wd[idx / 5][(idx % 5) * 8] = z;
        } else if (idx < 1280) {
            int j = idx - 960;
            float4 z = {0.f, 0.f, 0.f, 0.f};
            *(float4*)&dsh[j / 5][(j % 5) * 8] = z;
        }
    }
    __syncthreads();

#pragma unroll
    for (int i = 0; i < 3; ++i) {
        int idx = tid + i * 768;
        int row = idx / RR, c = idx % RR;
        Wd[row][c] = f2b(dtw[((size_t)(k * DI) + row) * RR + c]);
    }

    f32x4 acc1 = {};
    const ushort* arow = &xsb[(size_t)(bk * L_SZ + bm + rg * 16 + frow) * DI];
#pragma unroll
    for (int k0 = 0; k0 < 192; k0 += 32) {
        short8 af = *(const short8*)&arow[k0 + fk];
        short8 bv = *(const short8*)&Ws[cg * 16 + frow][k0 + fk];
        acc1 = __builtin_amdgcn_mfma_f32_16x16x32_bf16(af, bv, acc1, 0, 0, 0);
    }

    {
        int col = cg * 16 + frow;
#pragma unroll
        for (int r = 0; r < 4; ++r) {
            float v = acc1[r];
            int row = rg * 16 + orow + r;
            if (col >= RR && col < XD)
                xdbl[(size_t)(bk * L_SZ + bm + row) * XD + col] = v;
            if (col >= RR && col < RR + NS)
                bshL[row][col - RR] = v;               // B states for scan
            if (cg == 0 && col < RR)
                dsh[row][col] = f2b(v);
        }
    }
    __syncthreads();

    {
        int d = wave * 16 + frow;
        short8 bv = *(const short8*)&Wd[d][fk];
        float bias = dtb[k * DI + d];
#pragma unroll
        for (int rg2 = 0; rg2 < 4; ++rg2) {
            short8 af2 = *(const short8*)&dsh[rg2 * 16 + frow][fk];
            f32x4 a2 = {};
            a2 = __builtin_amdgcn_mfma_f32_16x16x32_bf16(af2, bv, a2, 0, 0, 0);
#pragma unroll
            for (int r = 0; r < 4; ++r) {
                float a = a2[r] + bias;
                float sp = (a > 20.f) ? a : log1pf(__expf(a));
                dts_b[(size_t)(bk * L_SZ + bm + rg2 * 16 + orow + r) * DI + d] = f2b(sp);
            }
        }
    }
    __syncthreads();    // drains vmcnt(0): dts_b stores visible to re-read

    // -------- scan pass A for the 2 chunks of this tile (384 threads) -----
    if (tid < 2 * DI) {
        const int d   = tid % DI;
        const int ch2 = tid / DI;                 // 0..1
        const int l0  = ch2 * CL;                 // row offset within tile
        const int gch = blockIdx.x * 2 + ch2;     // global chunk id
        const size_t gtok0 = (size_t)(bk * L_SZ + bm + l0);

        float Aa[NS], E[NS], S[NS];
        const float* ar = &A_logs[(size_t)(k * DI + d) * NS];
        bool fastp = true;
#pragma unroll
        for (int n = 0; n < NS; ++n) {
            Aa[n] = -__expf(ar[n]);
            E[n] = 1.f; S[n] = 0.f;
            fastp = fastp && (fabsf(Aa[n] + (float)(n + 1)) < 1e-4f * (n + 1));
        }

        if (fastp) {
            float P = 1.f;
#pragma unroll 4
            for (int l = 0; l < CL; ++l) {
                float dt = b2f(dts_b[(gtok0 + l) * DI + d]);
                float u  = b2f(xsb [(gtok0 + l) * DI + d]);
                float du = dt * u;
                const float* bl = bshL[l0 + l];
                float e1 = __expf(-dt);
                P *= e1;
                float e = e1;
                S[0] = fmaf(S[0], e, du * bl[0]);
#pragma unroll
                for (int n = 1; n < NS; ++n) {
                    e *= e1;
                    S[n] = fmaf(S[n], e, du * bl[n]);
                }
            }
            E[0] = P;
#pragma unroll
            for (int n = 1; n < NS; ++n) E[n] = E[n - 1] * P;
        } else {
#pragma unroll 4
            for (int l = 0; l < CL; ++l) {
                float dt = b2f(dts_b[(gtok0 + l) * DI + d]);
                float u  = b2f(xsb [(gtok0 + l) * DI + d]);
                float du = dt * u;
                const float* bl = bshL[l0 + l];
#pragma unroll
                for (int n = 0; n < NS; ++n) {
                    float e = __expf(dt * Aa[n]);
                    E[n] *= e;
                    S[n] = fmaf(S[n], e, du * bl[n]);
                }
            }
        }
        float* ep = &Ebuf[(size_t)((bk * NC + gch) * DI + d) * NS];
        float* sp = &Sbuf[(size_t)((bk * NC + gch) * DI + d) * NS];
#pragma unroll
        for (int n = 0; n < NS; ++n) { ep[n] = E[n]; sp[n] = S[n]; }
    }
}

// ---------------------------------------------------------------------------
// Scan pass B: chunk prefix; one thread per (bk,d,4n) -> float4 chains.
// Also zeroes the per-token LN stats buffer (free: independent memory).
// ---------------------------------------------------------------------------
__global__ __launch_bounds__(256) void scan_passB(
        const float* __restrict__ Ebuf, const float* __restrict__ Sbuf,
        float* __restrict__ Hstart, float* __restrict__ stats) {
    int t = blockIdx.x * 256 + threadIdx.x;       // 8*192*4 = 6144
    for (int z = t; z < MTOK * 2; z += 6144) stats[z] = 0.f;

    int bk = t / (DI * 4);
    int dn = (t % (DI * 4)) * 4;
    size_t off = (size_t)(bk * NC) * DI * NS + dn;
    const size_t stride = (size_t)DI * NS;

    float4 h = {0.f, 0.f, 0.f, 0.f};
    float4 e = *(const float4*)&Ebuf[off];
    float4 s = *(const float4*)&Sbuf[off];
    for (int c = 0; c < NC; ++c) {
        float4 en = {0.f,0.f,0.f,0.f}, sn = {0.f,0.f,0.f,0.f};
        if (c + 1 < NC) {
            en = *(const float4*)&Ebuf[off + stride];
            sn = *(const float4*)&Sbuf[off + stride];
        }
        *(float4*)&Hstart[off] = h;
        h.x = fmaf(e.x, h.x, s.x);
        h.y = fmaf(e.y, h.y, s.y);
        h.z = fmaf(e.z, h.z, s.z);
        h.w = fmaf(e.w, h.w, s.w);
        off += stride; e = en; s = sn;
    }
}

// ---------------------------------------------------------------------------
// Scan pass C: replay chunk with true h_start, emit y (bf16 spatial scatter)
// + accumulate per-token LN stats (sum, sumsq) via wave-reduce + atomicAdd.
// ---------------------------------------------------------------------------
__global__ __launch_bounds__(192) void scan_passC(
        const ushort* __restrict__ dts_b, const ushort* __restrict__ xsb,
        const float* __restrict__ xdbl, const float* __restrict__ A_logs,
        const float* __restrict__ Hstart, const float* __restrict__ Ds,
        ushort* __restrict__ ypre_b, float* __restrict__ stats) {
    int blk = blockIdx.x;
    int bk = blk / NC, ch = blk % NC;
    int d = threadIdx.x, k = bk % KG, b = bk / KG;
    int l0 = ch * CL;

    __shared__ float bsh[CL][NS];
    __shared__ float csh[CL][NS];
    for (int t = threadIdx.x; t < CL * NS; t += 192) {
        int l = t / NS, n = t % NS;
        const float* row = &xdbl[(size_t)(bk * L_SZ + l0 + l) * XD];
        bsh[l][n] = row[RR + n];
        csh[l][n] = row[RR + NS + n];
    }
    __syncthreads();

    float Aa[NS], h[NS];
    const float* ar = &A_logs[(size_t)(k * DI + d) * NS];
    const float* hp = &Hstart[(size_t)((bk * NC + ch) * DI + d) * NS];
    bool fast = true;
#pragma unroll
    for (int n = 0; n < NS; ++n) {
        Aa[n] = -__expf(ar[n]);
        h[n] = hp[n];
        fast = fast && (fabsf(Aa[n] + (float)(n + 1)) < 1e-4f * (n + 1));
    }
    float Dd = Ds[k * DI + d];

#pragma unroll 4
    for (int l = 0; l < CL; ++l) {
        float dt = b2f(dts_b[(size_t)(bk * L_SZ + l0 + l) * DI + d]);
        float u  = b2f(xsb [(size_t)(bk * L_SZ + l0 + l) * DI + d]);
        float du = dt * u;
        float4 b0 = *(const float4*)&bsh[l][0];
        float4 b1 = *(const float4*)&bsh[l][4];
        float4 b2 = *(const float4*)&bsh[l][8];
        float4 b3 = *(const float4*)&bsh[l][12];
        float Bv[NS] = {b0.x,b0.y,b0.z,b0.w, b1.x,b1.y,b1.z,b1.w,
                        b2.x,b2.y,b2.z,b2.w, b3.x,b3.y,b3.z,b3.w};
        float4 c0 = *(const float4*)&csh[l][0];
        float4 c1 = *(const float4*)&csh[l][4];
        float4 c2 = *(const float4*)&csh[l][8];
        float4 c3 = *(const float4*)&csh[l][12];
        float Cv[NS] = {c0.x,c0.y,c0.z,c0.w, c1.x,c1.y,c1.z,c1.w,
                        c2.x,c2.y,c2.z,c2.w, c3.x,c3.y,c3.z,c3.w};
        float p[NS];
        if (fast) {
            float e1 = __expf(-dt);
            float e = e1;
            h[0] = fmaf(h[0], e, du * Bv[0]);
            p[0] = h[0] * Cv[0];
#pragma unroll
            for (int n = 1; n < NS; ++n) {
                e *= e1;
                h[n] = fmaf(h[n], e, du * Bv[n]);
                p[n] = h[n] * Cv[n];
            }
        } else {
#pragma unroll
            for (int n = 0; n < NS; ++n) {
                float e = __expf(dt * Aa[n]);
                h[n] = fmaf(h[n], e, du * Bv[n]);
                p[n] = h[n] * Cv[n];
            }
        }
#pragma unroll
        for (int s = 8; s >= 1; s >>= 1)
#pragma unroll
            for (int n = 0; n < 8; ++n)
                if (n < s) p[n] = p[n] + p[n + s];
        float y = fmaf(Dd, u, p[0]);

        int lg = l0 + l;
        int pos;
        if      (k == 0) pos = lg;
        else if (k == 1) pos = (lg % H_SZ) * W_SZ + (lg / H_SZ);
        else if (k == 2) pos = L_SZ - 1 - lg;
        else { int j = L_SZ - 1 - lg; pos = (j % H_SZ) * W_SZ + (j / H_SZ); }

        // LN stats: all threads of a wave share the same token (same l).
        float s1 = y, s2 = y * y;
#pragma unroll
        for (int off = 32; off >= 1; off >>= 1) {
            s1 += __shfl_xor(s1, off, 64);
            s2 += __shfl_xor(s2, off, 64);
        }
        int tok = b * L_SZ + pos;
        if ((threadIdx.x & 63) == 0) {
            atomicAdd(&stats[tok * 2],     s1);
            atomicAdd(&stats[tok * 2 + 1], s2);
        }

        ypre_b[(size_t)tok * CIN + k * DI + d] = f2b(y);
    }
}

// ---------------------------------------------------------------------------
// Out-proj GEMM with fused LayerNorm on the A path.
// A = ypre (bf16, pre-norm); per-row mu/rstd finalized from the stats buffer;
// per-channel w/b applied during the bf16 re-cast. M=4608, N=384, K=768.
// ---------------------------------------------------------------------------
__global__ __launch_bounds__(256) void gemm2_ln(
        const ushort* __restrict__ Apre, const float* __restrict__ Bw,
        float* __restrict__ Cout, const float* __restrict__ stats,
        const float* __restrict__ lnw, const float* __restrict__ lnb) {
    constexpr int N = 384;
    constexpr int K = CIN;
    __shared__ ushort As[64][40];
    __shared__ ushort Bs[64][40];
    const int tid  = threadIdx.x;
    const int lane = tid & 63;
    const int wave = tid >> 6;
    const int wrow = wave * 16;
    const int bm = blockIdx.y * 64, bn = blockIdx.x * 64;
    const int frow = lane & 15;
    const int fk   = (lane >> 4) * 8;
    const int orow = (lane >> 4) * 4;
    const int row_t = tid >> 2, q = tid & 3;

    float s1 = stats[(bm + row_t) * 2];
    float s2 = stats[(bm + row_t) * 2 + 1];
    float mu   = s1 * (1.f / CIN);
    float var  = s2 * (1.f / CIN) - mu * mu;
    float rstd = rsqrtf(var + 1e-5f);

    f32x4 acc[4] = {};

    for (int k0 = 0; k0 < K; k0 += 32) {
        int c0 = k0 + q * 8;
        short8 sv = *(const short8*)&Apre[(size_t)(bm + row_t) * K + c0];
        float4 w0 = *(const float4*)&lnw[c0];
        float4 w1 = *(const float4*)&lnw[c0 + 4];
        float4 g0 = *(const float4*)&lnb[c0];
        float4 g1 = *(const float4*)&lnb[c0 + 4];
        float wv[8] = {w0.x,w0.y,w0.z,w0.w, w1.x,w1.y,w1.z,w1.w};
        float gv[8] = {g0.x,g0.y,g0.z,g0.w, g1.x,g1.y,g1.z,g1.w};
        short8 aval;
#pragma unroll
        for (int j = 0; j < 8; ++j)
            aval[j] = (short)f2b(fmaf((b2f((ushort)sv[j]) - mu) * rstd, wv[j], gv[j]));
        const float* bp = &Bw[(size_t)(bn + row_t) * K + c0];
        short8 bval = f2b8(*(const float4*)bp, *(const float4*)(bp + 4));

        __syncthreads();
        *(short8*)&As[row_t][q * 8] = aval;
        *(short8*)&Bs[row_t][q * 8] = bval;
        __syncthreads();

        short8 af = *(const short8*)&As[wrow + frow][fk];
        short8 bf[4];
#pragma unroll
        for (int ni = 0; ni < 4; ++ni)
            bf[ni] = *(const short8*)&Bs[ni * 16 + frow][fk];
#pragma unroll
        for (int ni = 0; ni < 4; ++ni)
            acc[ni] = __builtin_amdgcn_mfma_f32_16x16x32_bf16(af, bf[ni], acc[ni], 0, 0, 0);
    }

    int rbase = bm + wrow + orow;
#pragma unroll
    for (int ni = 0; ni < 4; ++ni) {
        int col = bn + ni * 16 + frow;
#pragma unroll
        for (int r = 0; r < 4; ++r)
            Cout[(size_t)(rbase + r) * N + col] = acc[ni][r];
    }
}

// ---------------------------------------------------------------------------
extern "C" void kernel_launch(void* const* d_in, const int* in_sizes, int n_in,
                              void* d_out, int out_size, void* d_ws, size_t ws_size,
                              hipStream_t stream) {
    const float* x    = (const float*)d_in[0];
    const float* inw  = (const float*)d_in[1];
    const float* cw   = (const float*)d_in[2];
    const float* cb   = (const float*)d_in[3];
    const float* xpw  = (const float*)d_in[4];
    const float* dtw  = (const float*)d_in[5];
    const float* dtb  = (const float*)d_in[6];
    const float* alog = (const float*)d_in[7];
    const float* Dsp  = (const float*)d_in[8];
    const float* lnw  = (const float*)d_in[9];
    const float* lnb  = (const float*)d_in[10];
    const float* outw = (const float*)d_in[11];
    float* out = (float*)d_out;

    float* ws = (float*)d_ws;
    const size_t SZ_BIG = (size_t)MTOK * CIN;            // 3,538,944
    const size_t SCAN_SL = (size_t)8 * NC * DI * NS;     // 1,769,472
    float* xz    = ws;                                   // bf16 in-proj out; later ypre_b
    float* xsbf  = xz  + SZ_BIG;                         // bf16 xs (float slots)
    float* dts   = xsbf + SZ_BIG / 2;                    // bf16 dts
    float* xdbl  = dts + SZ_BIG;                         // (8,L,44) fp32
    float* Ebuf  = xdbl + (size_t)8 * L_SZ * XD;
    float* Sbuf  = Ebuf + SCAN_SL;
    float* Hst   = Sbuf + SCAN_SL;
    float* stats = Hst + SCAN_SL;                        // (MTOK,2) fp32 LN sums
    // overlays (strictly sequential producer/consumer):
    ushort* xzb    = (ushort*)xz;     // gemm1 out (bf16) -> conv in
    ushort* xsb    = (ushort*)xsbf;   // conv -> xproj + scans
    ushort* dtsb   = (ushort*)dts;    // xproj -> scans
    ushort* ypre_b = (ushort*)xz;     // scanC out -> gemm2 A (xzb dead after conv)

    // 1. in-proj GEMM (bf16 MFMA, inline fp32->bf16 A-cast, bf16 C out)
    gemm_tn64<128, false, true><<<dim3(CIN / 64, MTOK / 128), 256, 0, stream>>>(
        x, inw, xzb, MTOK, CIN, 384);
    // 2. depthwise conv + SiLU + scatter (bf16 in/out)
    conv_silu_scatter<<<(B_SZ * H_SZ * W_SZ * CIN) / 256, 256, 0, stream>>>(xzb, cw, cb, xsb);
    // 3. fused MFMA x-projection + dt-projection + scan pass A
    xproj_dt_scanA<<<dim3(L_SZ / 64, 8), 768, 0, stream>>>(
        xsb, xpw, dtw, dtb, alog, xdbl, dtsb, Ebuf, Sbuf);
    // 4. chunk prefix (+ zero LN stats)
    scan_passB<<<(8 * DI * 4) / 256, 256, 0, stream>>>(Ebuf, Sbuf, Hst, stats);
    // 5. replay + y emit + LN stats accumulation
    scan_passC<<<8 * NC, 192, 0, stream>>>(dtsb, xsb, xdbl, alog, Hst, Dsp, ypre_b, stats);
    // 6. out-proj GEMM with fused LayerNorm on A
    gemm2_ln<<<dim3(384 / 64, MTOK / 64), 256, 0, stream>>>(
        ypre_b, outw, out, stats, lnw, lnb);
}

// Round 2
// 232.305 us; speedup vs baseline: 1.0525x; 1.0525x over previous
//
#include <hip/hip_runtime.h>
#include <hip/hip_bf16.h>

#define B_SZ   2
#define H_SZ   48
#define W_SZ   48
#define L_SZ   2304          // H*W
#define CIN    768           // C_INNER
#define KG     4
#define DI     192           // D_IN (channels per direction)
#define NS     16            // N_STATE
#define RR     12            // R_RANK
#define XD     44            // RR + 2*NS
#define MTOK   4608          // B*L
#define CL     32            // scan chunk length
#define NC     72            // L / CL

typedef __attribute__((ext_vector_type(8))) short short8;
typedef __attribute__((ext_vector_type(4))) float f32x4;

__device__ inline ushort f2b(float f) {
    uint u = __builtin_bit_cast(uint, f);
    u = (u + 0x7FFF + ((u >> 16) & 1)) >> 16;   // RNE to bf16
    return (ushort)u;
}
__device__ inline float b2f(ushort b) {
    uint u = ((uint)b) << 16;
    return __builtin_bit_cast(float, u);
}
__device__ inline short8 f2b8(float4 a, float4 b) {
    short8 r;
    r[0] = (short)f2b(a.x); r[1] = (short)f2b(a.y);
    r[2] = (short)f2b(a.z); r[3] = (short)f2b(a.w);
    r[4] = (short)f2b(b.x); r[5] = (short)f2b(b.y);
    r[6] = (short)f2b(b.z); r[7] = (short)f2b(b.w);
    return r;
}

// ---------------------------------------------------------------------------
// MFMA GEMM, TN=64 column tiles:  C[M,N] = A[M,K] * Bw[N,K]^T
// A bf16 (ABF) or fp32 cast inline; Bw fp32 cast inline.
// C stored fp32 (CBF=false) or bf16 (CBF=true). Waves stacked on M.
// ---------------------------------------------------------------------------
template<int TM, bool ABF, bool CBF>
__global__ __launch_bounds__(256) void gemm_tn64(
        const void* __restrict__ Av, const float* __restrict__ Bw,
        void* __restrict__ Cv, int M, int N, int K) {
    __shared__ ushort As[TM][40];
    __shared__ ushort Bs[64][40];
    const int tid  = threadIdx.x;
    const int lane = tid & 63;
    const int wave = tid >> 6;
    constexpr int MF = TM / 64;
    const int wrow = wave * (MF * 16);
    const int bm = blockIdx.y * TM, bn = blockIdx.x * 64;
    const int frow = lane & 15;
    const int fk   = (lane >> 4) * 8;
    const int orow = (lane >> 4) * 4;

    f32x4 acc[MF][4] = {};

    for (int k0 = 0; k0 < K; k0 += 32) {
        short8 aval[MF];
#pragma unroll
        for (int i = 0; i < MF; ++i) {
            int idx = tid + i * 256;
            int row = idx >> 2, q = idx & 3;
            if (ABF) {
                aval[i] = *(const short8*)&((const ushort*)Av)[(size_t)(bm + row) * K + k0 + q * 8];
            } else {
                const float* ap = &((const float*)Av)[(size_t)(bm + row) * K + k0 + q * 8];
                aval[i] = f2b8(*(const float4*)ap, *(const float4*)(ap + 4));
            }
        }
        const float* bp = &Bw[(size_t)(bn + (tid >> 2)) * K + k0 + (tid & 3) * 8];
        short8 bval = f2b8(*(const float4*)bp, *(const float4*)(bp + 4));

        __syncthreads();
#pragma unroll
        for (int i = 0; i < MF; ++i) {
            int idx = tid + i * 256;
            *(short8*)&As[idx >> 2][(idx & 3) * 8] = aval[i];
        }
        *(short8*)&Bs[tid >> 2][(tid & 3) * 8] = bval;
        __syncthreads();

        short8 af[MF], bf[4];
#pragma unroll
        for (int mi = 0; mi < MF; ++mi)
            af[mi] = *(const short8*)&As[wrow + mi * 16 + frow][fk];
#pragma unroll
        for (int ni = 0; ni < 4; ++ni)
            bf[ni] = *(const short8*)&Bs[ni * 16 + frow][fk];
#pragma unroll
        for (int mi = 0; mi < MF; ++mi)
#pragma unroll
            for (int ni = 0; ni < 4; ++ni)
                acc[mi][ni] = __builtin_amdgcn_mfma_f32_16x16x32_bf16(
                                  af[mi], bf[ni], acc[mi][ni], 0, 0, 0);
    }

#pragma unroll
    for (int mi = 0; mi < MF; ++mi) {
        int rbase = bm + wrow + mi * 16 + orow;
#pragma unroll
        for (int ni = 0; ni < 4; ++ni) {
            int col = bn + ni * 16 + frow;
#pragma unroll
            for (int r = 0; r < 4; ++r) {
                if (CBF)
                    ((ushort*)Cv)[(size_t)(rbase + r) * N + col] = f2b(acc[mi][ni][r]);
                else
                    ((float*)Cv)[(size_t)(rbase + r) * N + col] = acc[mi][ni][r];
            }
        }
    }
}

// ---------------------------------------------------------------------------
// Depthwise 3x3 conv (SAME) + bias + SiLU on bf16 NHWC input; scatter into
// the four scan orders xsb[b][k][l'][d] (bf16).
// ---------------------------------------------------------------------------
__global__ __launch_bounds__(256) void conv_silu_scatter(
        const ushort* __restrict__ xzb, const float* __restrict__ cw,
        const float* __restrict__ cb, ushort* __restrict__ xsb) {
    int idx = blockIdx.x * 256 + threadIdx.x;
    int c = idx % CIN;
    int rest = idx / CIN;
    int w = rest % W_SZ; rest /= W_SZ;
    int h = rest % H_SZ;
    int b = rest / H_SZ;

    float acc = cb[c];
#pragma unroll
    for (int dh = -1; dh <= 1; ++dh) {
        int hh = h + dh;
        if (hh < 0 || hh >= H_SZ) continue;
#pragma unroll
        for (int dw = -1; dw <= 1; ++dw) {
            int ww = w + dw;
            if (ww < 0 || ww >= W_SZ) continue;
            acc += b2f(xzb[(size_t)((b * H_SZ + hh) * W_SZ + ww) * CIN + c])
                 * cw[c * 9 + (dh + 1) * 3 + (dw + 1)];
        }
    }
    float s = acc / (1.f + __expf(-acc));   // SiLU

    int k = c / DI, d = c % DI;
    int lrow = h * W_SZ + w;
    int lcol = w * H_SZ + h;
    int l;
    if      (k == 0) l = lrow;
    else if (k == 1) l = lcol;
    else if (k == 2) l = L_SZ - 1 - lrow;
    else             l = L_SZ - 1 - lcol;
    xsb[(size_t)((b * KG + k) * L_SZ + l) * DI + d] = f2b(s);
}

// ---------------------------------------------------------------------------
// MFMA fused x-projection + dt-projection (768 threads = 12 waves).
// dts emitted as bf16.  (round-0 structure, scan NOT fused)
// ---------------------------------------------------------------------------
__global__ __launch_bounds__(768) void xproj_dt_mfma(
        const ushort* __restrict__ xsb, const float* __restrict__ xpw,
        const float* __restrict__ dtw, const float* __restrict__ dtb,
        float* __restrict__ xdbl, ushort* __restrict__ dts_b) {
    __shared__ ushort Ws[48][200];
    __shared__ ushort Wd[192][40];
    __shared__ ushort dsh[64][40];

    const int tid  = threadIdx.x;
    const int lane = tid & 63;
    const int wave = tid >> 6;        // 0..11
    const int bm = blockIdx.x * 64;
    const int bk = blockIdx.y;
    const int k  = bk & 3;
    const int frow = lane & 15;
    const int fk   = (lane >> 4) * 8;
    const int orow = (lane >> 4) * 4;
    const int rg = wave & 3;
    const int cg = wave >> 2;

#pragma unroll
    for (int i = 0; i < 3; ++i) {
        int idx = tid + i * 768;
        int row = idx / 48, g = idx % 48;
        ushort4 u = {0, 0, 0, 0};
        if (row < XD) {
            float4 v = *(const float4*)&xpw[((size_t)(k * XD) + row) * 192 + g * 4];
            u.x = f2b(v.x); u.y = f2b(v.y); u.z = f2b(v.z); u.w = f2b(v.w);
        }
        *(ushort4*)&Ws[row][g * 4] = u;
    }
#pragma unroll
    for (int i = 0; i < 2; ++i) {
        int idx = tid + i * 768;
        if (idx < 960) {
            float4 z = {0.f, 0.f, 0.f, 0.f};
            *(float4*)&Wd[idx / 5][(idx % 5) * 8] = z;
        } else if (idx < 1280) {
            int j = idx - 960;
            float4 z = {0.f, 0.f, 0.f, 0.f};
            *(float4*)&dsh[j / 5][(j % 5) * 8] = z;
        }
    }
    __syncthreads();

#pragma unroll
    for (int i = 0; i < 3; ++i) {
        int idx = tid + i * 768;
        int row = idx / RR, c = idx % RR;
        Wd[row][c] = f2b(dtw[((size_t)(k * DI) + row) * RR + c]);
    }

    f32x4 acc1 = {};
    const ushort* arow = &xsb[(size_t)(bk * L_SZ + bm + rg * 16 + frow) * DI];
#pragma unroll
    for (int k0 = 0; k0 < 192; k0 += 32) {
        short8 af = *(const short8*)&arow[k0 + fk];
        short8 bv = *(const short8*)&Ws[cg * 16 + frow][k0 + fk];
        acc1 = __builtin_amdgcn_mfma_f32_16x16x32_bf16(af, bv, acc1, 0, 0, 0);
    }

    {
        int col = cg * 16 + frow;
#pragma unroll
        for (int r = 0; r < 4; ++r) {
            float v = acc1[r];
            int row = rg * 16 + orow + r;
            if (col >= RR && col < XD)
                xdbl[(size_t)(bk * L_SZ + bm + row) * XD + col] = v;
            if (cg == 0 && col < RR)
                dsh[row][col] = f2b(v);
        }
    }
    __syncthreads();

    {
        int d = wave * 16 + frow;
        short8 bv = *(const short8*)&Wd[d][fk];
        float bias = dtb[k * DI + d];
#pragma unroll
        for (int rg2 = 0; rg2 < 4; ++rg2) {
            short8 af2 = *(const short8*)&dsh[rg2 * 16 + frow][fk];
            f32x4 a2 = {};
            a2 = __builtin_amdgcn_mfma_f32_16x16x32_bf16(af2, bv, a2, 0, 0, 0);
#pragma unroll
            for (int r = 0; r < 4; ++r) {
                float a = a2[r] + bias;
                float sp = (a > 20.f) ? a : log1pf(__expf(a));
                dts_b[(size_t)(bk * L_SZ + bm + rg2 * 16 + orow + r) * DI + d] = f2b(sp);
            }
        }
    }
}

// ---------------------------------------------------------------------------
// Scan pass A: per (bk, chunk, d, n) E = prod(e_l), S = local scan. CL=32.
// ---------------------------------------------------------------------------
__global__ __launch_bounds__(192) void scan_passA(
        const ushort* __restrict__ dts_b, const ushort* __restrict__ xsb,
        const float* __restrict__ xdbl, const float* __restrict__ A_logs,
        float* __restrict__ Ebuf, float* __restrict__ Sbuf) {
    int blk = blockIdx.x;
    int bk = blk / NC, ch = blk % NC;
    int d = threadIdx.x, k = bk % KG;
    int l0 = ch * CL;

    __shared__ float bsh[CL][NS];
    for (int t = threadIdx.x; t < CL * NS; t += 192) {
        int l = t / NS, n = t % NS;
        bsh[l][n] = xdbl[(size_t)(bk * L_SZ + l0 + l) * XD + RR + n];
    }
    __syncthreads();

    float Aa[NS], E[NS], S[NS];
    const float* ar = &A_logs[(size_t)(k * DI + d) * NS];
    bool fast = true;
#pragma unroll
    for (int n = 0; n < NS; ++n) {
        Aa[n] = -__expf(ar[n]);
        E[n] = 1.f; S[n] = 0.f;
        fast = fast && (fabsf(Aa[n] + (float)(n + 1)) < 1e-4f * (n + 1));
    }

    if (fast) {
        float P = 1.f;
#pragma unroll 4
        for (int l = 0; l < CL; ++l) {
            float dt = b2f(dts_b[(size_t)(bk * L_SZ + l0 + l) * DI + d]);
            float u  = b2f(xsb [(size_t)(bk * L_SZ + l0 + l) * DI + d]);
            float du = dt * u;
            float4 b0 = *(const float4*)&bsh[l][0];
            float4 b1 = *(const float4*)&bsh[l][4];
            float4 b2 = *(const float4*)&bsh[l][8];
            float4 b3 = *(const float4*)&bsh[l][12];
            float Bv[NS] = {b0.x,b0.y,b0.z,b0.w, b1.x,b1.y,b1.z,b1.w,
                            b2.x,b2.y,b2.z,b2.w, b3.x,b3.y,b3.z,b3.w};
            float e1 = __expf(-dt);
            P *= e1;
            float e = e1;
            S[0] = fmaf(S[0], e, du * Bv[0]);
#pragma unroll
            for (int n = 1; n < NS; ++n) {
                e *= e1;
                S[n] = fmaf(S[n], e, du * Bv[n]);
            }
        }
        E[0] = P;
#pragma unroll
        for (int n = 1; n < NS; ++n) E[n] = E[n - 1] * P;
    } else {
#pragma unroll 4
        for (int l = 0; l < CL; ++l) {
            float dt = b2f(dts_b[(size_t)(bk * L_SZ + l0 + l) * DI + d]);
            float u  = b2f(xsb [(size_t)(bk * L_SZ + l0 + l) * DI + d]);
            float du = dt * u;
            float4 b0 = *(const float4*)&bsh[l][0];
            float4 b1 = *(const float4*)&bsh[l][4];
            float4 b2 = *(const float4*)&bsh[l][8];
            float4 b3 = *(const float4*)&bsh[l][12];
            float Bv[NS] = {b0.x,b0.y,b0.z,b0.w, b1.x,b1.y,b1.z,b1.w,
                            b2.x,b2.y,b2.z,b2.w, b3.x,b3.y,b3.z,b3.w};
#pragma unroll
            for (int n = 0; n < NS; ++n) {
                float e = __expf(dt * Aa[n]);
                E[n] *= e;
                S[n] = fmaf(S[n], e, du * Bv[n]);
            }
        }
    }
    float* ep = &Ebuf[(size_t)((bk * NC + ch) * DI + d) * NS];
    float* sp = &Sbuf[(size_t)((bk * NC + ch) * DI + d) * NS];
#pragma unroll
    for (int n = 0; n < NS; ++n) { ep[n] = E[n]; sp[n] = S[n]; }
}

// ---------------------------------------------------------------------------
// Scan pass B: chunk prefix; one thread per (bk,d,4n) -> float4 chains.
// ---------------------------------------------------------------------------
__global__ __launch_bounds__(256) void scan_passB(
        const float* __restrict__ Ebuf, const float* __restrict__ Sbuf,
        float* __restrict__ Hstart) {
    int t = blockIdx.x * 256 + threadIdx.x;       // 8*192*4 = 6144
    int bk = t / (DI * 4);
    int dn = (t % (DI * 4)) * 4;
    size_t off = (size_t)(bk * NC) * DI * NS + dn;
    const size_t stride = (size_t)DI * NS;

    float4 h = {0.f, 0.f, 0.f, 0.f};
    float4 e = *(const float4*)&Ebuf[off];
    float4 s = *(const float4*)&Sbuf[off];
    for (int c = 0; c < NC; ++c) {
        float4 en = {0.f,0.f,0.f,0.f}, sn = {0.f,0.f,0.f,0.f};
        if (c + 1 < NC) {
            en = *(const float4*)&Ebuf[off + stride];
            sn = *(const float4*)&Sbuf[off + stride];
        }
        *(float4*)&Hstart[off] = h;
        h.x = fmaf(e.x, h.x, s.x);
        h.y = fmaf(e.y, h.y, s.y);
        h.z = fmaf(e.z, h.z, s.z);
        h.w = fmaf(e.w, h.w, s.w);
        off += stride; e = en; s = sn;
    }
}

// ---------------------------------------------------------------------------
// Scan pass C: replay chunk with true h_start, emit y (bf16 spatial scatter).
// (round-0 structure: no LN stats here)
// ---------------------------------------------------------------------------
__global__ __launch_bounds__(192) void scan_passC(
        const ushort* __restrict__ dts_b, const ushort* __restrict__ xsb,
        const float* __restrict__ xdbl, const float* __restrict__ A_logs,
        const float* __restrict__ Hstart, const float* __restrict__ Ds,
        ushort* __restrict__ ypre_b) {
    int blk = blockIdx.x;
    int bk = blk / NC, ch = blk % NC;
    int d = threadIdx.x, k = bk % KG, b = bk / KG;
    int l0 = ch * CL;

    __shared__ float bsh[CL][NS];
    __shared__ float csh[CL][NS];
    for (int t = threadIdx.x; t < CL * NS; t += 192) {
        int l = t / NS, n = t % NS;
        const float* row = &xdbl[(size_t)(bk * L_SZ + l0 + l) * XD];
        bsh[l][n] = row[RR + n];
        csh[l][n] = row[RR + NS + n];
    }
    __syncthreads();

    float Aa[NS], h[NS];
    const float* ar = &A_logs[(size_t)(k * DI + d) * NS];
    const float* hp = &Hstart[(size_t)((bk * NC + ch) * DI + d) * NS];
    bool fast = true;
#pragma unroll
    for (int n = 0; n < NS; ++n) {
        Aa[n] = -__expf(ar[n]);
        h[n] = hp[n];
        fast = fast && (fabsf(Aa[n] + (float)(n + 1)) < 1e-4f * (n + 1));
    }
    float Dd = Ds[k * DI + d];

#pragma unroll 4
    for (int l = 0; l < CL; ++l) {
        float dt = b2f(dts_b[(size_t)(bk * L_SZ + l0 + l) * DI + d]);
        float u  = b2f(xsb [(size_t)(bk * L_SZ + l0 + l) * DI + d]);
        float du = dt * u;
        float4 b0 = *(const float4*)&bsh[l][0];
        float4 b1 = *(const float4*)&bsh[l][4];
        float4 b2 = *(const float4*)&bsh[l][8];
        float4 b3 = *(const float4*)&bsh[l][12];
        float Bv[NS] = {b0.x,b0.y,b0.z,b0.w, b1.x,b1.y,b1.z,b1.w,
                        b2.x,b2.y,b2.z,b2.w, b3.x,b3.y,b3.z,b3.w};
        float4 c0 = *(const float4*)&csh[l][0];
        float4 c1 = *(const float4*)&csh[l][4];
        float4 c2 = *(const float4*)&csh[l][8];
        float4 c3 = *(const float4*)&csh[l][12];
        float Cv[NS] = {c0.x,c0.y,c0.z,c0.w, c1.x,c1.y,c1.z,c1.w,
                        c2.x,c2.y,c2.z,c2.w, c3.x,c3.y,c3.z,c3.w};
        float p[NS];
        if (fast) {
            float e1 = __expf(-dt);
            float e = e1;
            h[0] = fmaf(h[0], e, du * Bv[0]);
            p[0] = h[0] * Cv[0];
#pragma unroll
            for (int n = 1; n < NS; ++n) {
                e *= e1;
                h[n] = fmaf(h[n], e, du * Bv[n]);
                p[n] = h[n] * Cv[n];
            }
        } else {
#pragma unroll
            for (int n = 0; n < NS; ++n) {
                float e = __expf(dt * Aa[n]);
                h[n] = fmaf(h[n], e, du * Bv[n]);
                p[n] = h[n] * Cv[n];
            }
        }
#pragma unroll
        for (int s = 8; s >= 1; s >>= 1)
#pragma unroll
            for (int n = 0; n < 8; ++n)
                if (n < s) p[n] = p[n] + p[n + s];
        float y = fmaf(Dd, u, p[0]);

        int lg = l0 + l;
        int pos;
        if      (k == 0) pos = lg;
        else if (k == 1) pos = (lg % H_SZ) * W_SZ + (lg / H_SZ);
        else if (k == 2) pos = L_SZ - 1 - lg;
        else { int j = L_SZ - 1 - lg; pos = (j % H_SZ) * W_SZ + (j / H_SZ); }
        ypre_b[(size_t)(b * L_SZ + pos) * CIN + k * DI + d] = f2b(y);
    }
}

// ---------------------------------------------------------------------------
// Out-proj GEMM with fused LayerNorm on the A path (block-local self-stats).
// Pass 1: each block reads the full K=768 of its 64 A-rows (bf16) and computes
// per-row mu/rstd (reduce across the 4 lanes sharing a row). Pass 2: normal
// GEMM with LN applied during the bf16 A-recast. No atomics, no stats buffer.
// M=4608, N=384, K=768.
// ---------------------------------------------------------------------------
__global__ __launch_bounds__(256) void gemm2_ln(
        const ushort* __restrict__ Apre, const float* __restrict__ Bw,
        float* __restrict__ Cout,
        const float* __restrict__ lnw, const float* __restrict__ lnb) {
    constexpr int N = 384;
    constexpr int K = CIN;
    __shared__ ushort As[64][40];
    __shared__ ushort Bs[64][40];
    const int tid  = threadIdx.x;
    const int lane = tid & 63;
    const int wave = tid >> 6;
    const int wrow = wave * 16;
    const int bm = blockIdx.y * 64, bn = blockIdx.x * 64;
    const int frow = lane & 15;
    const int fk   = (lane >> 4) * 8;
    const int orow = (lane >> 4) * 4;
    const int row_t = tid >> 2, q = tid & 3;

    // ---- pass 1: LN stats for this block's 64 rows -----------------------
    const ushort* arow = &Apre[(size_t)(bm + row_t) * K];
    float s1 = 0.f, s2 = 0.f;
#pragma unroll 4
    for (int k0 = 0; k0 < K; k0 += 32) {
        short8 sv = *(const short8*)&arow[k0 + q * 8];
#pragma unroll
        for (int j = 0; j < 8; ++j) {
            float v = b2f((ushort)sv[j]);
            s1 += v;
            s2 = fmaf(v, v, s2);
        }
    }
    // threads {4r,4r+1,4r+2,4r+3} (adjacent lanes) share row r
    s1 += __shfl_xor(s1, 1, 64); s1 += __shfl_xor(s1, 2, 64);
    s2 += __shfl_xor(s2, 1, 64); s2 += __shfl_xor(s2, 2, 64);
    float mu   = s1 * (1.f / CIN);
    float var  = s2 * (1.f / CIN) - mu * mu;
    float rstd = rsqrtf(var + 1e-5f);

    // ---- pass 2: GEMM with LN fused into the A staging -------------------
    f32x4 acc[4] = {};

    for (int k0 = 0; k0 < K; k0 += 32) {
        int c0 = k0 + q * 8;
        short8 sv = *(const short8*)&arow[c0];
        float4 w0 = *(const float4*)&lnw[c0];
        float4 w1 = *(const float4*)&lnw[c0 + 4];
        float4 g0 = *(const float4*)&lnb[c0];
        float4 g1 = *(const float4*)&lnb[c0 + 4];
        float wv[8] = {w0.x,w0.y,w0.z,w0.w, w1.x,w1.y,w1.z,w1.w};
        float gv[8] = {g0.x,g0.y,g0.z,g0.w, g1.x,g1.y,g1.z,g1.w};
        short8 aval;
#pragma unroll
        for (int j = 0; j < 8; ++j)
            aval[j] = (short)f2b(fmaf((b2f((ushort)sv[j]) - mu) * rstd, wv[j], gv[j]));
        const float* bp = &Bw[(size_t)(bn + row_t) * K + c0];
        short8 bval = f2b8(*(const float4*)bp, *(const float4*)(bp + 4));

        __syncthreads();
        *(short8*)&As[row_t][q * 8] = aval;
        *(short8*)&Bs[row_t][q * 8] = bval;
        __syncthreads();

        short8 af = *(const short8*)&As[wrow + frow][fk];
        short8 bf[4];
#pragma unroll
        for (int ni = 0; ni < 4; ++ni)
            bf[ni] = *(const short8*)&Bs[ni * 16 + frow][fk];
#pragma unroll
        for (int ni = 0; ni < 4; ++ni)
            acc[ni] = __builtin_amdgcn_mfma_f32_16x16x32_bf16(af, bf[ni], acc[ni], 0, 0, 0);
    }

    int rbase = bm + wrow + orow;
#pragma unroll
    for (int ni = 0; ni < 4; ++ni) {
        int col = bn + ni * 16 + frow;
#pragma unroll
        for (int r = 0; r < 4; ++r)
            Cout[(size_t)(rbase + r) * N + col] = acc[ni][r];
    }
}

// ---------------------------------------------------------------------------
extern "C" void kernel_launch(void* const* d_in, const int* in_sizes, int n_in,
                              void* d_out, int out_size, void* d_ws, size_t ws_size,
                              hipStream_t stream) {
    const float* x    = (const float*)d_in[0];
    const float* inw  = (const float*)d_in[1];
    const float* cw   = (const float*)d_in[2];
    const float* cb   = (const float*)d_in[3];
    const float* xpw  = (const float*)d_in[4];
    const float* dtw  = (const float*)d_in[5];
    const float* dtb  = (const float*)d_in[6];
    const float* alog = (const float*)d_in[7];
    const float* Dsp  = (const float*)d_in[8];
    const float* lnw  = (const float*)d_in[9];
    const float* lnb  = (const float*)d_in[10];
    const float* outw = (const float*)d_in[11];
    float* out = (float*)d_out;

    float* ws = (float*)d_ws;
    const size_t SZ_BIG = (size_t)MTOK * CIN;            // 3,538,944
    const size_t SCAN_SL = (size_t)8 * NC * DI * NS;     // 1,769,472
    float* xz    = ws;                                   // bf16 in-proj out; later ypre_b
    float* xsbf  = xz  + SZ_BIG;                         // bf16 xs (float slots)
    float* dts   = xsbf + SZ_BIG / 2;                    // bf16 dts
    float* xdbl  = dts + SZ_BIG;                         // (8,L,44) fp32
    float* Ebuf  = xdbl + (size_t)8 * L_SZ * XD;
    float* Sbuf  = Ebuf + SCAN_SL;
    float* Hst   = Sbuf + SCAN_SL;
    // overlays (strictly sequential producer/consumer):
    ushort* xzb    = (ushort*)xz;     // gemm1 out (bf16) -> conv in
    ushort* xsb    = (ushort*)xsbf;   // conv -> xproj + scans
    ushort* dtsb   = (ushort*)dts;    // xproj -> scans
    ushort* ypre_b = (ushort*)xz;     // scanC out -> gemm2 A (xzb dead after conv)

    // 1. in-proj GEMM (bf16 MFMA, inline fp32->bf16 A-cast, bf16 C out)
    gemm_tn64<128, false, true><<<dim3(CIN / 64, MTOK / 128), 256, 0, stream>>>(
        x, inw, xzb, MTOK, CIN, 384);
    // 2. depthwise conv + SiLU + scatter (bf16 in/out)
    conv_silu_scatter<<<(B_SZ * H_SZ * W_SZ * CIN) / 256, 256, 0, stream>>>(xzb, cw, cb, xsb);
    // 3. fused MFMA x-projection + dt-projection (bf16 dts out)
    xproj_dt_mfma<<<dim3(L_SZ / 64, 8), 768, 0, stream>>>(xsb, xpw, dtw, dtb, xdbl, dtsb);
    // 4-6. chunked selective scan (CL=32)
    scan_passA<<<8 * NC, 192, 0, stream>>>(dtsb, xsb, xdbl, alog, Ebuf, Sbuf);
    scan_passB<<<(8 * DI * 4) / 256, 256, 0, stream>>>(Ebuf, Sbuf, Hst);
    scan_passC<<<8 * NC, 192, 0, stream>>>(dtsb, xsb, xdbl, alog, Hst, Dsp, ypre_b);
    // 7. out-proj GEMM with fused LayerNorm (block-local self-stats)
    gemm2_ln<<<dim3(384 / 64, MTOK / 64), 256, 0, stream>>>(
        ypre_b, outw, out, lnw, lnb);
}

// Round 3
// 213.110 us; speedup vs baseline: 1.1473x; 1.0901x over previous
//
#include <hip/hip_runtime.h>
#include <hip/hip_bf16.h>

#define B_SZ   2
#define H_SZ   48
#define W_SZ   48
#define L_SZ   2304          // H*W
#define CIN    768           // C_INNER
#define KG     4
#define DI     192           // D_IN (channels per direction)
#define NS     16            // N_STATE
#define RR     12            // R_RANK
#define XD     44            // RR + 2*NS
#define MTOK   4608          // B*L
#define CL     16            // scan chunk length (was 32)
#define NC     144           // L / CL

typedef __attribute__((ext_vector_type(8))) short short8;
typedef __attribute__((ext_vector_type(4))) float f32x4;

__device__ inline ushort f2b(float f) {
    uint u = __builtin_bit_cast(uint, f);
    u = (u + 0x7FFF + ((u >> 16) & 1)) >> 16;   // RNE to bf16
    return (ushort)u;
}
__device__ inline float b2f(ushort b) {
    uint u = ((uint)b) << 16;
    return __builtin_bit_cast(float, u);
}
__device__ inline short8 f2b8(float4 a, float4 b) {
    short8 r;
    r[0] = (short)f2b(a.x); r[1] = (short)f2b(a.y);
    r[2] = (short)f2b(a.z); r[3] = (short)f2b(a.w);
    r[4] = (short)f2b(b.x); r[5] = (short)f2b(b.y);
    r[6] = (short)f2b(b.z); r[7] = (short)f2b(b.w);
    return r;
}

// ---------------------------------------------------------------------------
// MFMA GEMM, TN=64 column tiles:  C[M,N] = A[M,K] * Bw[N,K]^T
// A bf16 (ABF) or fp32 cast inline; Bw fp32 cast inline.
// C stored fp32 (CBF=false) or bf16 (CBF=true). Waves stacked on M.
// ---------------------------------------------------------------------------
template<int TM, bool ABF, bool CBF>
__global__ __launch_bounds__(256) void gemm_tn64(
        const void* __restrict__ Av, const float* __restrict__ Bw,
        void* __restrict__ Cv, int M, int N, int K) {
    __shared__ ushort As[TM][40];
    __shared__ ushort Bs[64][40];
    const int tid  = threadIdx.x;
    const int lane = tid & 63;
    const int wave = tid >> 6;
    constexpr int MF = TM / 64;
    const int wrow = wave * (MF * 16);
    const int bm = blockIdx.y * TM, bn = blockIdx.x * 64;
    const int frow = lane & 15;
    const int fk   = (lane >> 4) * 8;
    const int orow = (lane >> 4) * 4;

    f32x4 acc[MF][4] = {};

    for (int k0 = 0; k0 < K; k0 += 32) {
        short8 aval[MF];
#pragma unroll
        for (int i = 0; i < MF; ++i) {
            int idx = tid + i * 256;
            int row = idx >> 2, q = idx & 3;
            if (ABF) {
                aval[i] = *(const short8*)&((const ushort*)Av)[(size_t)(bm + row) * K + k0 + q * 8];
            } else {
                const float* ap = &((const float*)Av)[(size_t)(bm + row) * K + k0 + q * 8];
                aval[i] = f2b8(*(const float4*)ap, *(const float4*)(ap + 4));
            }
        }
        const float* bp = &Bw[(size_t)(bn + (tid >> 2)) * K + k0 + (tid & 3) * 8];
        short8 bval = f2b8(*(const float4*)bp, *(const float4*)(bp + 4));

        __syncthreads();
#pragma unroll
        for (int i = 0; i < MF; ++i) {
            int idx = tid + i * 256;
            *(short8*)&As[idx >> 2][(idx & 3) * 8] = aval[i];
        }
        *(short8*)&Bs[tid >> 2][(tid & 3) * 8] = bval;
        __syncthreads();

        short8 af[MF], bf[4];
#pragma unroll
        for (int mi = 0; mi < MF; ++mi)
            af[mi] = *(const short8*)&As[wrow + mi * 16 + frow][fk];
#pragma unroll
        for (int ni = 0; ni < 4; ++ni)
            bf[ni] = *(const short8*)&Bs[ni * 16 + frow][fk];
#pragma unroll
        for (int mi = 0; mi < MF; ++mi)
#pragma unroll
            for (int ni = 0; ni < 4; ++ni)
                acc[mi][ni] = __builtin_amdgcn_mfma_f32_16x16x32_bf16(
                                  af[mi], bf[ni], acc[mi][ni], 0, 0, 0);
    }

#pragma unroll
    for (int mi = 0; mi < MF; ++mi) {
        int rbase = bm + wrow + mi * 16 + orow;
#pragma unroll
        for (int ni = 0; ni < 4; ++ni) {
            int col = bn + ni * 16 + frow;
#pragma unroll
            for (int r = 0; r < 4; ++r) {
                if (CBF)
                    ((ushort*)Cv)[(size_t)(rbase + r) * N + col] = f2b(acc[mi][ni][r]);
                else
                    ((float*)Cv)[(size_t)(rbase + r) * N + col] = acc[mi][ni][r];
            }
        }
    }
}

// ---------------------------------------------------------------------------
// Depthwise 3x3 conv (SAME) + bias + SiLU on bf16 NHWC input; scatter into
// the four scan orders xsb[b][k][l'][d] (bf16).
// ---------------------------------------------------------------------------
__global__ __launch_bounds__(256) void conv_silu_scatter(
        const ushort* __restrict__ xzb, const float* __restrict__ cw,
        const float* __restrict__ cb, ushort* __restrict__ xsb) {
    int idx = blockIdx.x * 256 + threadIdx.x;
    int c = idx % CIN;
    int rest = idx / CIN;
    int w = rest % W_SZ; rest /= W_SZ;
    int h = rest % H_SZ;
    int b = rest / H_SZ;

    float acc = cb[c];
#pragma unroll
    for (int dh = -1; dh <= 1; ++dh) {
        int hh = h + dh;
        if (hh < 0 || hh >= H_SZ) continue;
#pragma unroll
        for (int dw = -1; dw <= 1; ++dw) {
            int ww = w + dw;
            if (ww < 0 || ww >= W_SZ) continue;
            acc += b2f(xzb[(size_t)((b * H_SZ + hh) * W_SZ + ww) * CIN + c])
                 * cw[c * 9 + (dh + 1) * 3 + (dw + 1)];
        }
    }
    float s = acc * __builtin_amdgcn_rcpf(1.f + __expf(-acc));   // SiLU

    int k = c / DI, d = c % DI;
    int lrow = h * W_SZ + w;
    int lcol = w * H_SZ + h;
    int l;
    if      (k == 0) l = lrow;
    else if (k == 1) l = lcol;
    else if (k == 2) l = L_SZ - 1 - lrow;
    else             l = L_SZ - 1 - lcol;
    xsb[(size_t)((b * KG + k) * L_SZ + l) * DI + d] = f2b(s);
}

// ---------------------------------------------------------------------------
// MFMA fused x-projection + dt-projection, v2: 32-token tiles, 384 threads
// (6 waves = 2 row-groups x 3 col-groups), grid 72x8 = 576 blocks (2.25/CU).
// Fast softplus (v_exp + v_log, no libm log1pf). dts emitted as bf16.
// ---------------------------------------------------------------------------
__global__ __launch_bounds__(384) void xproj_dt_mfma(
        const ushort* __restrict__ xsb, const float* __restrict__ xpw,
        const float* __restrict__ dtw, const float* __restrict__ dtb,
        float* __restrict__ xdbl, ushort* __restrict__ dts_b) {
    __shared__ ushort Ws[48][200];      // x_proj_weight, bf16, rows 44..47 zero
    __shared__ ushort Wd[192][40];      // dt_projs_weight, cols 12..39 zero
    __shared__ ushort dsh[32][40];      // low-rank dts, cols 12..39 zero

    const int tid  = threadIdx.x;
    const int lane = tid & 63;
    const int wave = tid >> 6;        // 0..5
    const int bm = blockIdx.x * 32;
    const int bk = blockIdx.y;
    const int k  = bk & 3;
    const int frow = lane & 15;
    const int fk   = (lane >> 4) * 8;
    const int orow = (lane >> 4) * 4;
    const int rg = wave & 1;          // row group (16 tokens)
    const int cg = wave >> 1;         // col group (16 cols of Ws output)

    // stage Ws (48x192 bf16): 2304 ushort4 chunks
#pragma unroll
    for (int i = 0; i < 6; ++i) {
        int idx = tid + i * 384;
        int row = idx / 48, g = idx % 48;
        ushort4 u = {0, 0, 0, 0};
        if (row < XD) {
            float4 v = *(const float4*)&xpw[((size_t)(k * XD) + row) * 192 + g * 4];
            u.x = f2b(v.x); u.y = f2b(v.y); u.z = f2b(v.z); u.w = f2b(v.w);
        }
        *(ushort4*)&Ws[row][g * 4] = u;
    }
    // zero Wd (960 8-ushort chunks) and dsh (160 chunks)
#pragma unroll
    for (int i = 0; i < 3; ++i) {
        int idx = tid + i * 384;
        if (idx < 960) {
            float4 z = {0.f, 0.f, 0.f, 0.f};
            *(float4*)&Wd[idx / 5][(idx % 5) * 8] = z;
        } else if (idx < 1120) {
            int j = idx - 960;
            float4 z = {0.f, 0.f, 0.f, 0.f};
            *(float4*)&dsh[j / 5][(j % 5) * 8] = z;
        }
    }
    __syncthreads();

    // fill Wd cols 0..11 (after zeroing barrier)
#pragma unroll
    for (int i = 0; i < 6; ++i) {
        int idx = tid + i * 384;
        int row = idx / RR, c = idx % RR;
        Wd[row][c] = f2b(dtw[((size_t)(k * DI) + row) * RR + c]);
    }

    // x-projection: [32 x 192] x [44 x 192]^T
    f32x4 acc1 = {};
    const ushort* arow = &xsb[(size_t)(bk * L_SZ + bm + rg * 16 + frow) * DI];
#pragma unroll
    for (int k0 = 0; k0 < 192; k0 += 32) {
        short8 af = *(const short8*)&arow[k0 + fk];
        short8 bv = *(const short8*)&Ws[cg * 16 + frow][k0 + fk];
        acc1 = __builtin_amdgcn_mfma_f32_16x16x32_bf16(af, bv, acc1, 0, 0, 0);
    }

    {
        int col = cg * 16 + frow;
#pragma unroll
        for (int r = 0; r < 4; ++r) {
            float v = acc1[r];
            int row = rg * 16 + orow + r;
            if (col >= RR && col < XD)
                xdbl[(size_t)(bk * L_SZ + bm + row) * XD + col] = v;
            if (cg == 0 && col < RR)
                dsh[row][col] = f2b(v);
        }
    }
    __syncthreads();

    // dt-projection: [32 x 12] x [12 x 192]; 12 d-tiles, 2 per wave
#pragma unroll
    for (int t = 0; t < 2; ++t) {
        int d = (wave * 2 + t) * 16 + frow;
        short8 bv = *(const short8*)&Wd[d][fk];
        float bias = dtb[k * DI + d];
#pragma unroll
        for (int rg2 = 0; rg2 < 2; ++rg2) {
            short8 af2 = *(const short8*)&dsh[rg2 * 16 + frow][fk];
            f32x4 a2 = {};
            a2 = __builtin_amdgcn_mfma_f32_16x16x32_bf16(af2, bv, a2, 0, 0, 0);
#pragma unroll
            for (int r = 0; r < 4; ++r) {
                float a = a2[r] + bias;
                // softplus via HW transcendentals: max(a,0) + log(1+exp(-|a|))
                float sp = fmaxf(a, 0.f) + __logf(1.f + __expf(-fabsf(a)));
                dts_b[(size_t)(bk * L_SZ + bm + rg2 * 16 + orow + r) * DI + d] = f2b(sp);
            }
        }
    }
}

// ---------------------------------------------------------------------------
// Scan pass A: per (bk, chunk, d, n) E = prod(e_l), S = local scan. CL=16.
// ---------------------------------------------------------------------------
__global__ __launch_bounds__(192) void scan_passA(
        const ushort* __restrict__ dts_b, const ushort* __restrict__ xsb,
        const float* __restrict__ xdbl, const float* __restrict__ A_logs,
        float* __restrict__ Ebuf, float* __restrict__ Sbuf) {
    int blk = blockIdx.x;
    int bk = blk / NC, ch = blk % NC;
    int d = threadIdx.x, k = bk % KG;
    int l0 = ch * CL;

    __shared__ float bsh[CL][NS];
    for (int t = threadIdx.x; t < CL * NS; t += 192) {
        int l = t / NS, n = t % NS;
        bsh[l][n] = xdbl[(size_t)(bk * L_SZ + l0 + l) * XD + RR + n];
    }
    __syncthreads();

    float Aa[NS], E[NS], S[NS];
    const float* ar = &A_logs[(size_t)(k * DI + d) * NS];
    bool fast = true;
#pragma unroll
    for (int n = 0; n < NS; ++n) {
        Aa[n] = -__expf(ar[n]);
        E[n] = 1.f; S[n] = 0.f;
        fast = fast && (fabsf(Aa[n] + (float)(n + 1)) < 1e-4f * (n + 1));
    }

    if (fast) {
        float P = 1.f;
#pragma unroll 4
        for (int l = 0; l < CL; ++l) {
            float dt = b2f(dts_b[(size_t)(bk * L_SZ + l0 + l) * DI + d]);
            float u  = b2f(xsb [(size_t)(bk * L_SZ + l0 + l) * DI + d]);
            float du = dt * u;
            float4 b0 = *(const float4*)&bsh[l][0];
            float4 b1 = *(const float4*)&bsh[l][4];
            float4 b2 = *(const float4*)&bsh[l][8];
            float4 b3 = *(const float4*)&bsh[l][12];
            float Bv[NS] = {b0.x,b0.y,b0.z,b0.w, b1.x,b1.y,b1.z,b1.w,
                            b2.x,b2.y,b2.z,b2.w, b3.x,b3.y,b3.z,b3.w};
            float e1 = __expf(-dt);
            P *= e1;
            float e = e1;
            S[0] = fmaf(S[0], e, du * Bv[0]);
#pragma unroll
            for (int n = 1; n < NS; ++n) {
                e *= e1;
                S[n] = fmaf(S[n], e, du * Bv[n]);
            }
        }
        E[0] = P;
#pragma unroll
        for (int n = 1; n < NS; ++n) E[n] = E[n - 1] * P;
    } else {
#pragma unroll 4
        for (int l = 0; l < CL; ++l) {
            float dt = b2f(dts_b[(size_t)(bk * L_SZ + l0 + l) * DI + d]);
            float u  = b2f(xsb [(size_t)(bk * L_SZ + l0 + l) * DI + d]);
            float du = dt * u;
            float4 b0 = *(const float4*)&bsh[l][0];
            float4 b1 = *(const float4*)&bsh[l][4];
            float4 b2 = *(const float4*)&bsh[l][8];
            float4 b3 = *(const float4*)&bsh[l][12];
            float Bv[NS] = {b0.x,b0.y,b0.z,b0.w, b1.x,b1.y,b1.z,b1.w,
                            b2.x,b2.y,b2.z,b2.w, b3.x,b3.y,b3.z,b3.w};
#pragma unroll
            for (int n = 0; n < NS; ++n) {
                float e = __expf(dt * Aa[n]);
                E[n] *= e;
                S[n] = fmaf(S[n], e, du * Bv[n]);
            }
        }
    }
    float* ep = &Ebuf[(size_t)((bk * NC + ch) * DI + d) * NS];
    float* sp = &Sbuf[(size_t)((bk * NC + ch) * DI + d) * NS];
#pragma unroll
    for (int n = 0; n < NS; ++n) { ep[n] = E[n]; sp[n] = S[n]; }
}

// ---------------------------------------------------------------------------
// Scan pass B: chunk prefix; one thread per (bk,d,4n) -> float4 chains.
// ---------------------------------------------------------------------------
__global__ __launch_bounds__(256) void scan_passB(
        const float* __restrict__ Ebuf, const float* __restrict__ Sbuf,
        float* __restrict__ Hstart) {
    int t = blockIdx.x * 256 + threadIdx.x;       // 8*192*4 = 6144
    int bk = t / (DI * 4);
    int dn = (t % (DI * 4)) * 4;
    size_t off = (size_t)(bk * NC) * DI * NS + dn;
    const size_t stride = (size_t)DI * NS;

    float4 h = {0.f, 0.f, 0.f, 0.f};
    float4 e = *(const float4*)&Ebuf[off];
    float4 s = *(const float4*)&Sbuf[off];
    for (int c = 0; c < NC; ++c) {
        float4 en = {0.f,0.f,0.f,0.f}, sn = {0.f,0.f,0.f,0.f};
        if (c + 1 < NC) {
            en = *(const float4*)&Ebuf[off + stride];
            sn = *(const float4*)&Sbuf[off + stride];
        }
        *(float4*)&Hstart[off] = h;
        h.x = fmaf(e.x, h.x, s.x);
        h.y = fmaf(e.y, h.y, s.y);
        h.z = fmaf(e.z, h.z, s.z);
        h.w = fmaf(e.w, h.w, s.w);
        off += stride; e = en; s = sn;
    }
}

// ---------------------------------------------------------------------------
// Scan pass C: replay chunk with true h_start, emit y (bf16 spatial scatter).
// ---------------------------------------------------------------------------
__global__ __launch_bounds__(192) void scan_passC(
        const ushort* __restrict__ dts_b, const ushort* __restrict__ xsb,
        const float* __restrict__ xdbl, const float* __restrict__ A_logs,
        const float* __restrict__ Hstart, const float* __restrict__ Ds,
        ushort* __restrict__ ypre_b) {
    int blk = blockIdx.x;
    int bk = blk / NC, ch = blk % NC;
    int d = threadIdx.x, k = bk % KG, b = bk / KG;
    int l0 = ch * CL;

    __shared__ float bsh[CL][NS];
    __shared__ float csh[CL][NS];
    for (int t = threadIdx.x; t < CL * NS; t += 192) {
        int l = t / NS, n = t % NS;
        const float* row = &xdbl[(size_t)(bk * L_SZ + l0 + l) * XD];
        bsh[l][n] = row[RR + n];
        csh[l][n] = row[RR + NS + n];
    }
    __syncthreads();

    float Aa[NS], h[NS];
    const float* ar = &A_logs[(size_t)(k * DI + d) * NS];
    const float* hp = &Hstart[(size_t)((bk * NC + ch) * DI + d) * NS];
    bool fast = true;
#pragma unroll
    for (int n = 0; n < NS; ++n) {
        Aa[n] = -__expf(ar[n]);
        h[n] = hp[n];
        fast = fast && (fabsf(Aa[n] + (float)(n + 1)) < 1e-4f * (n + 1));
    }
    float Dd = Ds[k * DI + d];

#pragma unroll 4
    for (int l = 0; l < CL; ++l) {
        float dt = b2f(dts_b[(size_t)(bk * L_SZ + l0 + l) * DI + d]);
        float u  = b2f(xsb [(size_t)(bk * L_SZ + l0 + l) * DI + d]);
        float du = dt * u;
        float4 b0 = *(const float4*)&bsh[l][0];
        float4 b1 = *(const float4*)&bsh[l][4];
        float4 b2 = *(const float4*)&bsh[l][8];
        float4 b3 = *(const float4*)&bsh[l][12];
        float Bv[NS] = {b0.x,b0.y,b0.z,b0.w, b1.x,b1.y,b1.z,b1.w,
                        b2.x,b2.y,b2.z,b2.w, b3.x,b3.y,b3.z,b3.w};
        float4 c0 = *(const float4*)&csh[l][0];
        float4 c1 = *(const float4*)&csh[l][4];
        float4 c2 = *(const float4*)&csh[l][8];
        float4 c3 = *(const float4*)&csh[l][12];
        float Cv[NS] = {c0.x,c0.y,c0.z,c0.w, c1.x,c1.y,c1.z,c1.w,
                        c2.x,c2.y,c2.z,c2.w, c3.x,c3.y,c3.z,c3.w};
        float p[NS];
        if (fast) {
            float e1 = __expf(-dt);
            float e = e1;
            h[0] = fmaf(h[0], e, du * Bv[0]);
            p[0] = h[0] * Cv[0];
#pragma unroll
            for (int n = 1; n < NS; ++n) {
                e *= e1;
                h[n] = fmaf(h[n], e, du * Bv[n]);
                p[n] = h[n] * Cv[n];
            }
        } else {
#pragma unroll
            for (int n = 0; n < NS; ++n) {
                float e = __expf(dt * Aa[n]);
                h[n] = fmaf(h[n], e, du * Bv[n]);
                p[n] = h[n] * Cv[n];
            }
        }
#pragma unroll
        for (int s = 8; s >= 1; s >>= 1)
#pragma unroll
            for (int n = 0; n < 8; ++n)
                if (n < s) p[n] = p[n] + p[n + s];
        float y = fmaf(Dd, u, p[0]);

        int lg = l0 + l;
        int pos;
        if      (k == 0) pos = lg;
        else if (k == 1) pos = (lg % H_SZ) * W_SZ + (lg / H_SZ);
        else if (k == 2) pos = L_SZ - 1 - lg;
        else { int j = L_SZ - 1 - lg; pos = (j % H_SZ) * W_SZ + (j / H_SZ); }
        ypre_b[(size_t)(b * L_SZ + pos) * CIN + k * DI + d] = f2b(y);
    }
}

// ---------------------------------------------------------------------------
// LayerNorm over CIN=768; bf16 in, bf16 out (stats in fp32).
// ---------------------------------------------------------------------------
__global__ __launch_bounds__(256) void layernorm_bf16(
        const ushort* __restrict__ y, ushort* __restrict__ yb,
        const float* __restrict__ w, const float* __restrict__ bg) {
    int wave = threadIdx.x >> 6, lane = threadIdx.x & 63;
    int tok = blockIdx.x * 4 + wave;
    const ushort* row = &y[(size_t)tok * CIN];
    ushort* rowo = &yb[(size_t)tok * CIN];
    float v[12];
    float s = 0.f;
#pragma unroll
    for (int i = 0; i < 12; ++i) { v[i] = b2f(row[lane + i * 64]); s += v[i]; }
#pragma unroll
    for (int off = 32; off >= 1; off >>= 1) s += __shfl_xor(s, off, 64);
    float mu = s * (1.f / CIN);
    float s2 = 0.f;
#pragma unroll
    for (int i = 0; i < 12; ++i) { float t = v[i] - mu; s2 += t * t; }
#pragma unroll
    for (int off = 32; off >= 1; off >>= 1) s2 += __shfl_xor(s2, off, 64);
    float rstd = rsqrtf(s2 * (1.f / CIN) + 1e-5f);
#pragma unroll
    for (int i = 0; i < 12; ++i)
        rowo[lane + i * 64] =
            f2b((v[i] - mu) * rstd * w[lane + i * 64] + bg[lane + i * 64]);
}

// ---------------------------------------------------------------------------
extern "C" void kernel_launch(void* const* d_in, const int* in_sizes, int n_in,
                              void* d_out, int out_size, void* d_ws, size_t ws_size,
                              hipStream_t stream) {
    const float* x    = (const float*)d_in[0];
    const float* inw  = (const float*)d_in[1];
    const float* cw   = (const float*)d_in[2];
    const float* cb   = (const float*)d_in[3];
    const float* xpw  = (const float*)d_in[4];
    const float* dtw  = (const float*)d_in[5];
    const float* dtb  = (const float*)d_in[6];
    const float* alog = (const float*)d_in[7];
    const float* Dsp  = (const float*)d_in[8];
    const float* lnw  = (const float*)d_in[9];
    const float* lnb  = (const float*)d_in[10];
    const float* outw = (const float*)d_in[11];
    float* out = (float*)d_out;

    float* ws = (float*)d_ws;
    const size_t SZ_BIG = (size_t)MTOK * CIN;            // 3,538,944
    const size_t SCAN_SL = (size_t)8 * NC * DI * NS;     // 3,538,944 (CL=16)
    float* xz    = ws;                                   // bf16 in-proj out; later ypre_b
    float* xsbf  = xz  + SZ_BIG;                         // bf16 xs (float slots)
    float* dts   = xsbf + SZ_BIG / 2;                    // bf16 dts; later ynrm_b
    float* xdbl  = dts + SZ_BIG;                         // (8,L,44) fp32
    float* Ebuf  = xdbl + (size_t)8 * L_SZ * XD;
    float* Sbuf  = Ebuf + SCAN_SL;
    float* Hst   = Sbuf + SCAN_SL;
    // overlays (strictly sequential producer/consumer):
    ushort* xzb    = (ushort*)xz;     // gemm1 out (bf16) -> conv in
    ushort* xsb    = (ushort*)xsbf;   // conv -> xproj + scans
    ushort* dtsb   = (ushort*)dts;    // xproj -> scans
    ushort* ypre_b = (ushort*)xz;     // scanC out -> LN in (xzb dead after conv)
    ushort* ynrm_b = (ushort*)dts;    // LN out -> out-proj (dtsb dead after scanC)

    // 1. in-proj GEMM (bf16 MFMA, inline fp32->bf16 A-cast, bf16 C out)
    gemm_tn64<128, false, true><<<dim3(CIN / 64, MTOK / 128), 256, 0, stream>>>(
        x, inw, xzb, MTOK, CIN, 384);
    // 2. depthwise conv + SiLU + scatter (bf16 in/out)
    conv_silu_scatter<<<(B_SZ * H_SZ * W_SZ * CIN) / 256, 256, 0, stream>>>(xzb, cw, cb, xsb);
    // 3. fused MFMA x-projection + dt-projection (32-token tiles, 576 blocks)
    xproj_dt_mfma<<<dim3(L_SZ / 32, 8), 384, 0, stream>>>(xsb, xpw, dtw, dtb, xdbl, dtsb);
    // 4-6. chunked selective scan (CL=16)
    scan_passA<<<8 * NC, 192, 0, stream>>>(dtsb, xsb, xdbl, alog, Ebuf, Sbuf);
    scan_passB<<<(8 * DI * 4) / 256, 256, 0, stream>>>(Ebuf, Sbuf, Hst);
    scan_passC<<<8 * NC, 192, 0, stream>>>(dtsb, xsb, xdbl, alog, Hst, Dsp, ypre_b);
    // 7. LayerNorm: bf16 in, bf16 out
    layernorm_bf16<<<MTOK / 4, 256, 0, stream>>>(ypre_b, ynrm_b, lnw, lnb);
    // 8. out-proj GEMM (bf16 A, inline-cast B, fp32 out)
    gemm_tn64<64, true, false><<<dim3(384 / 64, MTOK / 64), 256, 0, stream>>>(
        ynrm_b, outw, out, MTOK, 384, CIN);
}

// Round 4
// 197.653 us; speedup vs baseline: 1.2370x; 1.0782x over previous
//
#include <hip/hip_runtime.h>
#include <hip/hip_bf16.h>

#define B_SZ   2
#define H_SZ   48
#define W_SZ   48
#define L_SZ   2304          // H*W
#define CIN    768           // C_INNER
#define KG     4
#define DI     192           // D_IN (channels per direction)
#define NS     16            // N_STATE
#define RR     12            // R_RANK
#define XD     44            // RR + 2*NS
#define MTOK   4608          // B*L
#define CL     16            // scan chunk length
#define NC     144           // L / CL

typedef __attribute__((ext_vector_type(8))) short short8;
typedef __attribute__((ext_vector_type(4))) float f32x4;

__device__ inline ushort f2b(float f) {
    uint u = __builtin_bit_cast(uint, f);
    u = (u + 0x7FFF + ((u >> 16) & 1)) >> 16;   // RNE to bf16
    return (ushort)u;
}
__device__ inline float b2f(ushort b) {
    uint u = ((uint)b) << 16;
    return __builtin_bit_cast(float, u);
}
__device__ inline short8 f2b8(float4 a, float4 b) {
    short8 r;
    r[0] = (short)f2b(a.x); r[1] = (short)f2b(a.y);
    r[2] = (short)f2b(a.z); r[3] = (short)f2b(a.w);
    r[4] = (short)f2b(b.x); r[5] = (short)f2b(b.y);
    r[6] = (short)f2b(b.z); r[7] = (short)f2b(b.w);
    return r;
}

// ---------------------------------------------------------------------------
// MFMA GEMM, TN=64 column tiles:  C[M,N] = A[M,K] * Bw[N,K]^T
// A bf16 (ABF) or fp32 cast inline; Bw fp32 cast inline.
// C stored fp32 (CBF=false) or bf16 (CBF=true). Waves stacked on M.
// ---------------------------------------------------------------------------
template<int TM, bool ABF, bool CBF>
__global__ __launch_bounds__(256) void gemm_tn64(
        const void* __restrict__ Av, const float* __restrict__ Bw,
        void* __restrict__ Cv, int M, int N, int K) {
    __shared__ ushort As[TM][40];
    __shared__ ushort Bs[64][40];
    const int tid  = threadIdx.x;
    const int lane = tid & 63;
    const int wave = tid >> 6;
    constexpr int MF = TM / 64;
    const int wrow = wave * (MF * 16);
    const int bm = blockIdx.y * TM, bn = blockIdx.x * 64;
    const int frow = lane & 15;
    const int fk   = (lane >> 4) * 8;
    const int orow = (lane >> 4) * 4;

    f32x4 acc[MF][4] = {};

    for (int k0 = 0; k0 < K; k0 += 32) {
        short8 aval[MF];
#pragma unroll
        for (int i = 0; i < MF; ++i) {
            int idx = tid + i * 256;
            int row = idx >> 2, q = idx & 3;
            if (ABF) {
                aval[i] = *(const short8*)&((const ushort*)Av)[(size_t)(bm + row) * K + k0 + q * 8];
            } else {
                const float* ap = &((const float*)Av)[(size_t)(bm + row) * K + k0 + q * 8];
                aval[i] = f2b8(*(const float4*)ap, *(const float4*)(ap + 4));
            }
        }
        const float* bp = &Bw[(size_t)(bn + (tid >> 2)) * K + k0 + (tid & 3) * 8];
        short8 bval = f2b8(*(const float4*)bp, *(const float4*)(bp + 4));

        __syncthreads();
#pragma unroll
        for (int i = 0; i < MF; ++i) {
            int idx = tid + i * 256;
            *(short8*)&As[idx >> 2][(idx & 3) * 8] = aval[i];
        }
        *(short8*)&Bs[tid >> 2][(tid & 3) * 8] = bval;
        __syncthreads();

        short8 af[MF], bf[4];
#pragma unroll
        for (int mi = 0; mi < MF; ++mi)
            af[mi] = *(const short8*)&As[wrow + mi * 16 + frow][fk];
#pragma unroll
        for (int ni = 0; ni < 4; ++ni)
            bf[ni] = *(const short8*)&Bs[ni * 16 + frow][fk];
#pragma unroll
        for (int mi = 0; mi < MF; ++mi)
#pragma unroll
            for (int ni = 0; ni < 4; ++ni)
                acc[mi][ni] = __builtin_amdgcn_mfma_f32_16x16x32_bf16(
                                  af[mi], bf[ni], acc[mi][ni], 0, 0, 0);
    }

#pragma unroll
    for (int mi = 0; mi < MF; ++mi) {
        int rbase = bm + wrow + mi * 16 + orow;
#pragma unroll
        for (int ni = 0; ni < 4; ++ni) {
            int col = bn + ni * 16 + frow;
#pragma unroll
            for (int r = 0; r < 4; ++r) {
                if (CBF)
                    ((ushort*)Cv)[(size_t)(rbase + r) * N + col] = f2b(acc[mi][ni][r]);
                else
                    ((float*)Cv)[(size_t)(rbase + r) * N + col] = acc[mi][ni][r];
            }
        }
    }
}

// ---------------------------------------------------------------------------
// Depthwise 3x3 conv (SAME) + bias + SiLU on bf16 NHWC input; scatter into
// the four scan orders xsb[b][k][l'][d] (bf16).
// ---------------------------------------------------------------------------
__global__ __launch_bounds__(256) void conv_silu_scatter(
        const ushort* __restrict__ xzb, const float* __restrict__ cw,
        const float* __restrict__ cb, ushort* __restrict__ xsb) {
    int idx = blockIdx.x * 256 + threadIdx.x;
    int c = idx % CIN;
    int rest = idx / CIN;
    int w = rest % W_SZ; rest /= W_SZ;
    int h = rest % H_SZ;
    int b = rest / H_SZ;

    float acc = cb[c];
#pragma unroll
    for (int dh = -1; dh <= 1; ++dh) {
        int hh = h + dh;
        if (hh < 0 || hh >= H_SZ) continue;
#pragma unroll
        for (int dw = -1; dw <= 1; ++dw) {
            int ww = w + dw;
            if (ww < 0 || ww >= W_SZ) continue;
            acc += b2f(xzb[(size_t)((b * H_SZ + hh) * W_SZ + ww) * CIN + c])
                 * cw[c * 9 + (dh + 1) * 3 + (dw + 1)];
        }
    }
    float s = acc * __builtin_amdgcn_rcpf(1.f + __expf(-acc));   // SiLU

    int k = c / DI, d = c % DI;
    int lrow = h * W_SZ + w;
    int lcol = w * H_SZ + h;
    int l;
    if      (k == 0) l = lrow;
    else if (k == 1) l = lcol;
    else if (k == 2) l = L_SZ - 1 - lrow;
    else             l = L_SZ - 1 - lcol;
    xsb[(size_t)((b * KG + k) * L_SZ + l) * DI + d] = f2b(s);
}

// ---------------------------------------------------------------------------
// MFMA fused x-projection + dt-projection, v2: 32-token tiles, 384 threads
// (6 waves = 2 row-groups x 3 col-groups), grid 72x8 = 576 blocks (2.25/CU).
// Fast softplus (v_exp + v_log, no libm log1pf). dts emitted as bf16.
// ---------------------------------------------------------------------------
__global__ __launch_bounds__(384) void xproj_dt_mfma(
        const ushort* __restrict__ xsb, const float* __restrict__ xpw,
        const float* __restrict__ dtw, const float* __restrict__ dtb,
        float* __restrict__ xdbl, ushort* __restrict__ dts_b) {
    __shared__ ushort Ws[48][200];      // x_proj_weight, bf16, rows 44..47 zero
    __shared__ ushort Wd[192][40];      // dt_projs_weight, cols 12..39 zero
    __shared__ ushort dsh[32][40];      // low-rank dts, cols 12..39 zero

    const int tid  = threadIdx.x;
    const int lane = tid & 63;
    const int wave = tid >> 6;        // 0..5
    const int bm = blockIdx.x * 32;
    const int bk = blockIdx.y;
    const int k  = bk & 3;
    const int frow = lane & 15;
    const int fk   = (lane >> 4) * 8;
    const int orow = (lane >> 4) * 4;
    const int rg = wave & 1;          // row group (16 tokens)
    const int cg = wave >> 1;         // col group (16 cols of Ws output)

    // stage Ws (48x192 bf16): 2304 ushort4 chunks
#pragma unroll
    for (int i = 0; i < 6; ++i) {
        int idx = tid + i * 384;
        int row = idx / 48, g = idx % 48;
        ushort4 u = {0, 0, 0, 0};
        if (row < XD) {
            float4 v = *(const float4*)&xpw[((size_t)(k * XD) + row) * 192 + g * 4];
            u.x = f2b(v.x); u.y = f2b(v.y); u.z = f2b(v.z); u.w = f2b(v.w);
        }
        *(ushort4*)&Ws[row][g * 4] = u;
    }
    // zero Wd (960 8-ushort chunks) and dsh (160 chunks)
#pragma unroll
    for (int i = 0; i < 3; ++i) {
        int idx = tid + i * 384;
        if (idx < 960) {
            float4 z = {0.f, 0.f, 0.f, 0.f};
            *(float4*)&Wd[idx / 5][(idx % 5) * 8] = z;
        } else if (idx < 1120) {
            int j = idx - 960;
            float4 z = {0.f, 0.f, 0.f, 0.f};
            *(float4*)&dsh[j / 5][(j % 5) * 8] = z;
        }
    }
    __syncthreads();

    // fill Wd cols 0..11 (after zeroing barrier)
#pragma unroll
    for (int i = 0; i < 6; ++i) {
        int idx = tid + i * 384;
        int row = idx / RR, c = idx % RR;
        Wd[row][c] = f2b(dtw[((size_t)(k * DI) + row) * RR + c]);
    }

    // x-projection: [32 x 192] x [44 x 192]^T
    f32x4 acc1 = {};
    const ushort* arow = &xsb[(size_t)(bk * L_SZ + bm + rg * 16 + frow) * DI];
#pragma unroll
    for (int k0 = 0; k0 < 192; k0 += 32) {
        short8 af = *(const short8*)&arow[k0 + fk];
        short8 bv = *(const short8*)&Ws[cg * 16 + frow][k0 + fk];
        acc1 = __builtin_amdgcn_mfma_f32_16x16x32_bf16(af, bv, acc1, 0, 0, 0);
    }

    {
        int col = cg * 16 + frow;
#pragma unroll
        for (int r = 0; r < 4; ++r) {
            float v = acc1[r];
            int row = rg * 16 + orow + r;
            if (col >= RR && col < XD)
                xdbl[(size_t)(bk * L_SZ + bm + row) * XD + col] = v;
            if (cg == 0 && col < RR)
                dsh[row][col] = f2b(v);
        }
    }
    __syncthreads();

    // dt-projection: [32 x 12] x [12 x 192]; 12 d-tiles, 2 per wave
#pragma unroll
    for (int t = 0; t < 2; ++t) {
        int d = (wave * 2 + t) * 16 + frow;
        short8 bv = *(const short8*)&Wd[d][fk];
        float bias = dtb[k * DI + d];
#pragma unroll
        for (int rg2 = 0; rg2 < 2; ++rg2) {
            short8 af2 = *(const short8*)&dsh[rg2 * 16 + frow][fk];
            f32x4 a2 = {};
            a2 = __builtin_amdgcn_mfma_f32_16x16x32_bf16(af2, bv, a2, 0, 0, 0);
#pragma unroll
            for (int r = 0; r < 4; ++r) {
                float a = a2[r] + bias;
                // softplus via HW transcendentals: max(a,0) + log(1+exp(-|a|))
                float sp = fmaxf(a, 0.f) + __logf(1.f + __expf(-fabsf(a)));
                dts_b[(size_t)(bk * L_SZ + bm + rg2 * 16 + orow + r) * DI + d] = f2b(sp);
            }
        }
    }
}

// ---------------------------------------------------------------------------
// Scan pass A: per (bk, chunk, d, n) E = prod(e_l), S = local scan. CL=16.
// ---------------------------------------------------------------------------
__global__ __launch_bounds__(192) void scan_passA(
        const ushort* __restrict__ dts_b, const ushort* __restrict__ xsb,
        const float* __restrict__ xdbl, const float* __restrict__ A_logs,
        float* __restrict__ Ebuf, float* __restrict__ Sbuf) {
    int blk = blockIdx.x;
    int bk = blk / NC, ch = blk % NC;
    int d = threadIdx.x, k = bk % KG;
    int l0 = ch * CL;

    __shared__ float bsh[CL][NS];
    for (int t = threadIdx.x; t < CL * NS; t += 192) {
        int l = t / NS, n = t % NS;
        bsh[l][n] = xdbl[(size_t)(bk * L_SZ + l0 + l) * XD + RR + n];
    }
    __syncthreads();

    float Aa[NS], E[NS], S[NS];
    const float* ar = &A_logs[(size_t)(k * DI + d) * NS];
    bool fast = true;
#pragma unroll
    for (int n = 0; n < NS; ++n) {
        Aa[n] = -__expf(ar[n]);
        E[n] = 1.f; S[n] = 0.f;
        fast = fast && (fabsf(Aa[n] + (float)(n + 1)) < 1e-4f * (n + 1));
    }

    if (fast) {
        float P = 1.f;
#pragma unroll 4
        for (int l = 0; l < CL; ++l) {
            float dt = b2f(dts_b[(size_t)(bk * L_SZ + l0 + l) * DI + d]);
            float u  = b2f(xsb [(size_t)(bk * L_SZ + l0 + l) * DI + d]);
            float du = dt * u;
            float4 b0 = *(const float4*)&bsh[l][0];
            float4 b1 = *(const float4*)&bsh[l][4];
            float4 b2 = *(const float4*)&bsh[l][8];
            float4 b3 = *(const float4*)&bsh[l][12];
            float Bv[NS] = {b0.x,b0.y,b0.z,b0.w, b1.x,b1.y,b1.z,b1.w,
                            b2.x,b2.y,b2.z,b2.w, b3.x,b3.y,b3.z,b3.w};
            float e1 = __expf(-dt);
            P *= e1;
            float e = e1;
            S[0] = fmaf(S[0], e, du * Bv[0]);
#pragma unroll
            for (int n = 1; n < NS; ++n) {
                e *= e1;
                S[n] = fmaf(S[n], e, du * Bv[n]);
            }
        }
        E[0] = P;
#pragma unroll
        for (int n = 1; n < NS; ++n) E[n] = E[n - 1] * P;
    } else {
#pragma unroll 4
        for (int l = 0; l < CL; ++l) {
            float dt = b2f(dts_b[(size_t)(bk * L_SZ + l0 + l) * DI + d]);
            float u  = b2f(xsb [(size_t)(bk * L_SZ + l0 + l) * DI + d]);
            float du = dt * u;
            float4 b0 = *(const float4*)&bsh[l][0];
            float4 b1 = *(const float4*)&bsh[l][4];
            float4 b2 = *(const float4*)&bsh[l][8];
            float4 b3 = *(const float4*)&bsh[l][12];
            float Bv[NS] = {b0.x,b0.y,b0.z,b0.w, b1.x,b1.y,b1.z,b1.w,
                            b2.x,b2.y,b2.z,b2.w, b3.x,b3.y,b3.z,b3.w};
#pragma unroll
            for (int n = 0; n < NS; ++n) {
                float e = __expf(dt * Aa[n]);
                E[n] *= e;
                S[n] = fmaf(S[n], e, du * Bv[n]);
            }
        }
    }
    float* ep = &Ebuf[(size_t)((bk * NC + ch) * DI + d) * NS];
    float* sp = &Sbuf[(size_t)((bk * NC + ch) * DI + d) * NS];
#pragma unroll
    for (int n = 0; n < NS; ++n) { ep[n] = E[n]; sp[n] = S[n]; }
}

// ---------------------------------------------------------------------------
// Scan pass B v2: chunk prefix, software-pipelined prefetch depth 8.
// One thread per (bk,d,4n); 96 blocks x 64 threads (was 24x256) so ~96 CUs
// issue loads concurrently. Two statically-indexed register groups (A/B)
// alternate: while group X is consumed, group Y's 8+8 float4 loads are in
// flight -> per-iteration wait ~latency/8 instead of full L3 latency.
// NC=144 = 9 * 16 exactly (no tail).
// ---------------------------------------------------------------------------
__global__ __launch_bounds__(64) void scan_passB(
        const float* __restrict__ Ebuf, const float* __restrict__ Sbuf,
        float* __restrict__ Hstart) {
    constexpr int P = 8;
    int t = blockIdx.x * 64 + threadIdx.x;        // 8*192*4 = 6144 threads
    int bk = t / (DI * 4);
    int dn = (t % (DI * 4)) * 4;
    const size_t stride = (size_t)DI * NS;
    size_t off  = (size_t)(bk * NC) * stride + dn;   // store cursor
    size_t offL = off;                                // load cursor

    float4 eA[P], sA[P], eB[P], sB[P];
    float4 h = {0.f, 0.f, 0.f, 0.f};

    // prologue: load group 0 into A
#pragma unroll
    for (int j = 0; j < P; ++j) {
        eA[j] = *(const float4*)&Ebuf[offL + (size_t)j * stride];
        sA[j] = *(const float4*)&Sbuf[offL + (size_t)j * stride];
    }
    offL += (size_t)P * stride;

    for (int c = 0; c < NC; c += 2 * P) {
        // issue loads for group c+P into B (always valid: c+P <= 136 < 144)
#pragma unroll
        for (int j = 0; j < P; ++j) {
            eB[j] = *(const float4*)&Ebuf[offL + (size_t)j * stride];
            sB[j] = *(const float4*)&Sbuf[offL + (size_t)j * stride];
        }
        offL += (size_t)P * stride;

        // process group A
#pragma unroll
        for (int j = 0; j < P; ++j) {
            *(float4*)&Hstart[off + (size_t)j * stride] = h;
            h.x = fmaf(eA[j].x, h.x, sA[j].x);
            h.y = fmaf(eA[j].y, h.y, sA[j].y);
            h.z = fmaf(eA[j].z, h.z, sA[j].z);
            h.w = fmaf(eA[j].w, h.w, sA[j].w);
        }
        off += (size_t)P * stride;

        // issue loads for group c+2P into A (skip on last iteration)
        if (c + 2 * P < NC) {
#pragma unroll
            for (int j = 0; j < P; ++j) {
                eA[j] = *(const float4*)&Ebuf[offL + (size_t)j * stride];
                sA[j] = *(const float4*)&Sbuf[offL + (size_t)j * stride];
            }
        }
        offL += (size_t)P * stride;

        // process group B
#pragma unroll
        for (int j = 0; j < P; ++j) {
            *(float4*)&Hstart[off + (size_t)j * stride] = h;
            h.x = fmaf(eB[j].x, h.x, sB[j].x);
            h.y = fmaf(eB[j].y, h.y, sB[j].y);
            h.z = fmaf(eB[j].z, h.z, sB[j].z);
            h.w = fmaf(eB[j].w, h.w, sB[j].w);
        }
        off += (size_t)P * stride;
    }
}

// ---------------------------------------------------------------------------
// Scan pass C: replay chunk with true h_start, emit y (bf16 spatial scatter).
// ---------------------------------------------------------------------------
__global__ __launch_bounds__(192) void scan_passC(
        const ushort* __restrict__ dts_b, const ushort* __restrict__ xsb,
        const float* __restrict__ xdbl, const float* __restrict__ A_logs,
        const float* __restrict__ Hstart, const float* __restrict__ Ds,
        ushort* __restrict__ ypre_b) {
    int blk = blockIdx.x;
    int bk = blk / NC, ch = blk % NC;
    int d = threadIdx.x, k = bk % KG, b = bk / KG;
    int l0 = ch * CL;

    __shared__ float bsh[CL][NS];
    __shared__ float csh[CL][NS];
    for (int t = threadIdx.x; t < CL * NS; t += 192) {
        int l = t / NS, n = t % NS;
        const float* row = &xdbl[(size_t)(bk * L_SZ + l0 + l) * XD];
        bsh[l][n] = row[RR + n];
        csh[l][n] = row[RR + NS + n];
    }
    __syncthreads();

    float Aa[NS], h[NS];
    const float* ar = &A_logs[(size_t)(k * DI + d) * NS];
    const float* hp = &Hstart[(size_t)((bk * NC + ch) * DI + d) * NS];
    bool fast = true;
#pragma unroll
    for (int n = 0; n < NS; ++n) {
        Aa[n] = -__expf(ar[n]);
        h[n] = hp[n];
        fast = fast && (fabsf(Aa[n] + (float)(n + 1)) < 1e-4f * (n + 1));
    }
    float Dd = Ds[k * DI + d];

#pragma unroll 4
    for (int l = 0; l < CL; ++l) {
        float dt = b2f(dts_b[(size_t)(bk * L_SZ + l0 + l) * DI + d]);
        float u  = b2f(xsb [(size_t)(bk * L_SZ + l0 + l) * DI + d]);
        float du = dt * u;
        float4 b0 = *(const float4*)&bsh[l][0];
        float4 b1 = *(const float4*)&bsh[l][4];
        float4 b2 = *(const float4*)&bsh[l][8];
        float4 b3 = *(const float4*)&bsh[l][12];
        float Bv[NS] = {b0.x,b0.y,b0.z,b0.w, b1.x,b1.y,b1.z,b1.w,
                        b2.x,b2.y,b2.z,b2.w, b3.x,b3.y,b3.z,b3.w};
        float4 c0 = *(const float4*)&csh[l][0];
        float4 c1 = *(const float4*)&csh[l][4];
        float4 c2 = *(const float4*)&csh[l][8];
        float4 c3 = *(const float4*)&csh[l][12];
        float Cv[NS] = {c0.x,c0.y,c0.z,c0.w, c1.x,c1.y,c1.z,c1.w,
                        c2.x,c2.y,c2.z,c2.w, c3.x,c3.y,c3.z,c3.w};
        float p[NS];
        if (fast) {
            float e1 = __expf(-dt);
            float e = e1;
            h[0] = fmaf(h[0], e, du * Bv[0]);
            p[0] = h[0] * Cv[0];
#pragma unroll
            for (int n = 1; n < NS; ++n) {
                e *= e1;
                h[n] = fmaf(h[n], e, du * Bv[n]);
                p[n] = h[n] * Cv[n];
            }
        } else {
#pragma unroll
            for (int n = 0; n < NS; ++n) {
                float e = __expf(dt * Aa[n]);
                h[n] = fmaf(h[n], e, du * Bv[n]);
                p[n] = h[n] * Cv[n];
            }
        }
#pragma unroll
        for (int s = 8; s >= 1; s >>= 1)
#pragma unroll
            for (int n = 0; n < 8; ++n)
                if (n < s) p[n] = p[n] + p[n + s];
        float y = fmaf(Dd, u, p[0]);

        int lg = l0 + l;
        int pos;
        if      (k == 0) pos = lg;
        else if (k == 1) pos = (lg % H_SZ) * W_SZ + (lg / H_SZ);
        else if (k == 2) pos = L_SZ - 1 - lg;
        else { int j = L_SZ - 1 - lg; pos = (j % H_SZ) * W_SZ + (j / H_SZ); }
        ypre_b[(size_t)(b * L_SZ + pos) * CIN + k * DI + d] = f2b(y);
    }
}

// ---------------------------------------------------------------------------
// LayerNorm over CIN=768; bf16 in, bf16 out (stats in fp32).
// ---------------------------------------------------------------------------
__global__ __launch_bounds__(256) void layernorm_bf16(
        const ushort* __restrict__ y, ushort* __restrict__ yb,
        const float* __restrict__ w, const float* __restrict__ bg) {
    int wave = threadIdx.x >> 6, lane = threadIdx.x & 63;
    int tok = blockIdx.x * 4 + wave;
    const ushort* row = &y[(size_t)tok * CIN];
    ushort* rowo = &yb[(size_t)tok * CIN];
    float v[12];
    float s = 0.f;
#pragma unroll
    for (int i = 0; i < 12; ++i) { v[i] = b2f(row[lane + i * 64]); s += v[i]; }
#pragma unroll
    for (int off = 32; off >= 1; off >>= 1) s += __shfl_xor(s, off, 64);
    float mu = s * (1.f / CIN);
    float s2 = 0.f;
#pragma unroll
    for (int i = 0; i < 12; ++i) { float t = v[i] - mu; s2 += t * t; }
#pragma unroll
    for (int off = 32; off >= 1; off >>= 1) s2 += __shfl_xor(s2, off, 64);
    float rstd = rsqrtf(s2 * (1.f / CIN) + 1e-5f);
#pragma unroll
    for (int i = 0; i < 12; ++i)
        rowo[lane + i * 64] =
            f2b((v[i] - mu) * rstd * w[lane + i * 64] + bg[lane + i * 64]);
}

// ---------------------------------------------------------------------------
extern "C" void kernel_launch(void* const* d_in, const int* in_sizes, int n_in,
                              void* d_out, int out_size, void* d_ws, size_t ws_size,
                              hipStream_t stream) {
    const float* x    = (const float*)d_in[0];
    const float* inw  = (const float*)d_in[1];
    const float* cw   = (const float*)d_in[2];
    const float* cb   = (const float*)d_in[3];
    const float* xpw  = (const float*)d_in[4];
    const float* dtw  = (const float*)d_in[5];
    const float* dtb  = (const float*)d_in[6];
    const float* alog = (const float*)d_in[7];
    const float* Dsp  = (const float*)d_in[8];
    const float* lnw  = (const float*)d_in[9];
    const float* lnb  = (const float*)d_in[10];
    const float* outw = (const float*)d_in[11];
    float* out = (float*)d_out;

    float* ws = (float*)d_ws;
    const size_t SZ_BIG = (size_t)MTOK * CIN;            // 3,538,944
    const size_t SCAN_SL = (size_t)8 * NC * DI * NS;     // 3,538,944 (CL=16)
    float* xz    = ws;                                   // bf16 in-proj out; later ypre_b
    float* xsbf  = xz  + SZ_BIG;                         // bf16 xs (float slots)
    float* dts   = xsbf + SZ_BIG / 2;                    // bf16 dts; later ynrm_b
    float* xdbl  = dts + SZ_BIG;                         // (8,L,44) fp32
    float* Ebuf  = xdbl + (size_t)8 * L_SZ * XD;
    float* Sbuf  = Ebuf + SCAN_SL;
    float* Hst   = Sbuf + SCAN_SL;
    // overlays (strictly sequential producer/consumer):
    ushort* xzb    = (ushort*)xz;     // gemm1 out (bf16) -> conv in
    ushort* xsb    = (ushort*)xsbf;   // conv -> xproj + scans
    ushort* dtsb   = (ushort*)dts;    // xproj -> scans
    ushort* ypre_b = (ushort*)xz;     // scanC out -> LN in (xzb dead after conv)
    ushort* ynrm_b = (ushort*)dts;    // LN out -> out-proj (dtsb dead after scanC)

    // 1. in-proj GEMM (bf16 MFMA, inline fp32->bf16 A-cast, bf16 C out)
    gemm_tn64<128, false, true><<<dim3(CIN / 64, MTOK / 128), 256, 0, stream>>>(
        x, inw, xzb, MTOK, CIN, 384);
    // 2. depthwise conv + SiLU + scatter (bf16 in/out)
    conv_silu_scatter<<<(B_SZ * H_SZ * W_SZ * CIN) / 256, 256, 0, stream>>>(xzb, cw, cb, xsb);
    // 3. fused MFMA x-projection + dt-projection (32-token tiles, 576 blocks)
    xproj_dt_mfma<<<dim3(L_SZ / 32, 8), 384, 0, stream>>>(xsb, xpw, dtw, dtb, xdbl, dtsb);
    // 4-6. chunked selective scan (CL=16)
    scan_passA<<<8 * NC, 192, 0, stream>>>(dtsb, xsb, xdbl, alog, Ebuf, Sbuf);
    scan_passB<<<(8 * DI * 4) / 64, 64, 0, stream>>>(Ebuf, Sbuf, Hst);
    scan_passC<<<8 * NC, 192, 0, stream>>>(dtsb, xsb, xdbl, alog, Hst, Dsp, ypre_b);
    // 7. LayerNorm: bf16 in, bf16 out
    layernorm_bf16<<<MTOK / 4, 256, 0, stream>>>(ypre_b, ynrm_b, lnw, lnb);
    // 8. out-proj GEMM (bf16 A, inline-cast B, fp32 out)
    gemm_tn64<64, true, false><<<dim3(384 / 64, MTOK / 64), 256, 0, stream>>>(
        ynrm_b, outw, out, MTOK, 384, CIN);
}

// Round 6
// 184.637 us; speedup vs baseline: 1.3242x; 1.0705x over previous
//
#include <hip/hip_runtime.h>
#include <hip/hip_bf16.h>

#define B_SZ   2
#define H_SZ   48
#define W_SZ   48
#define L_SZ   2304          // H*W
#define CIN    768           // C_INNER
#define KG     4
#define DI     192           // D_IN (channels per direction)
#define NS     16            // N_STATE
#define RR     12            // R_RANK
#define XD     44            // RR + 2*NS
#define MTOK   4608          // B*L
#define CL     16            // scan chunk length
#define NC     144           // L / CL

typedef __attribute__((ext_vector_type(8))) short short8;
typedef __attribute__((ext_vector_type(4))) float f32x4;

__device__ inline ushort f2b(float f) {
    uint u = __builtin_bit_cast(uint, f);
    u = (u + 0x7FFF + ((u >> 16) & 1)) >> 16;   // RNE to bf16
    return (ushort)u;
}
__device__ inline float b2f(ushort b) {
    uint u = ((uint)b) << 16;
    return __builtin_bit_cast(float, u);
}
__device__ inline short8 f2b8(float4 a, float4 b) {
    short8 r;
    r[0] = (short)f2b(a.x); r[1] = (short)f2b(a.y);
    r[2] = (short)f2b(a.z); r[3] = (short)f2b(a.w);
    r[4] = (short)f2b(b.x); r[5] = (short)f2b(b.y);
    r[6] = (short)f2b(b.z); r[7] = (short)f2b(b.w);
    return r;
}

// ---------------------------------------------------------------------------
// MFMA GEMM, TN=64 column tiles:  C[M,N] = A[M,K] * Bw[N,K]^T
// ---------------------------------------------------------------------------
template<int TM, bool ABF, bool CBF>
__global__ __launch_bounds__(256) void gemm_tn64(
        const void* __restrict__ Av, const float* __restrict__ Bw,
        void* __restrict__ Cv, int M, int N, int K) {
    __shared__ ushort As[TM][40];
    __shared__ ushort Bs[64][40];
    const int tid  = threadIdx.x;
    const int lane = tid & 63;
    const int wave = tid >> 6;
    constexpr int MF = TM / 64;
    const int wrow = wave * (MF * 16);
    const int bm = blockIdx.y * TM, bn = blockIdx.x * 64;
    const int frow = lane & 15;
    const int fk   = (lane >> 4) * 8;
    const int orow = (lane >> 4) * 4;

    f32x4 acc[MF][4] = {};

    for (int k0 = 0; k0 < K; k0 += 32) {
        short8 aval[MF];
#pragma unroll
        for (int i = 0; i < MF; ++i) {
            int idx = tid + i * 256;
            int row = idx >> 2, q = idx & 3;
            if (ABF) {
                aval[i] = *(const short8*)&((const ushort*)Av)[(size_t)(bm + row) * K + k0 + q * 8];
            } else {
                const float* ap = &((const float*)Av)[(size_t)(bm + row) * K + k0 + q * 8];
                aval[i] = f2b8(*(const float4*)ap, *(const float4*)(ap + 4));
            }
        }
        const float* bp = &Bw[(size_t)(bn + (tid >> 2)) * K + k0 + (tid & 3) * 8];
        short8 bval = f2b8(*(const float4*)bp, *(const float4*)(bp + 4));

        __syncthreads();
#pragma unroll
        for (int i = 0; i < MF; ++i) {
            int idx = tid + i * 256;
            *(short8*)&As[idx >> 2][(idx & 3) * 8] = aval[i];
        }
        *(short8*)&Bs[tid >> 2][(tid & 3) * 8] = bval;
        __syncthreads();

        short8 af[MF], bf[4];
#pragma unroll
        for (int mi = 0; mi < MF; ++mi)
            af[mi] = *(const short8*)&As[wrow + mi * 16 + frow][fk];
#pragma unroll
        for (int ni = 0; ni < 4; ++ni)
            bf[ni] = *(const short8*)&Bs[ni * 16 + frow][fk];
#pragma unroll
        for (int mi = 0; mi < MF; ++mi)
#pragma unroll
            for (int ni = 0; ni < 4; ++ni)
                acc[mi][ni] = __builtin_amdgcn_mfma_f32_16x16x32_bf16(
                                  af[mi], bf[ni], acc[mi][ni], 0, 0, 0);
    }

#pragma unroll
    for (int mi = 0; mi < MF; ++mi) {
        int rbase = bm + wrow + mi * 16 + orow;
#pragma unroll
        for (int ni = 0; ni < 4; ++ni) {
            int col = bn + ni * 16 + frow;
#pragma unroll
            for (int r = 0; r < 4; ++r) {
                if (CBF)
                    ((ushort*)Cv)[(size_t)(rbase + r) * N + col] = f2b(acc[mi][ni][r]);
                else
                    ((float*)Cv)[(size_t)(rbase + r) * N + col] = acc[mi][ni][r];
            }
        }
    }
}

// ---------------------------------------------------------------------------
// Depthwise 3x3 conv + bias + SiLU, v2: 8 channels per thread (short8 loads,
// float4 weight loads, short8 store). 1728 blocks x 256 threads.
// ---------------------------------------------------------------------------
__global__ __launch_bounds__(256) void conv_silu_scatter(
        const ushort* __restrict__ xzb, const float* __restrict__ cw,
        const float* __restrict__ cb, ushort* __restrict__ xsb) {
    int g = blockIdx.x * 256 + threadIdx.x;     // 442368 total
    int c8 = g % 96;
    int pos = g / 96;
    int w = pos % W_SZ;
    int h = (pos / W_SZ) % H_SZ;
    int b = pos / (W_SZ * H_SZ);
    int c0 = c8 * 8;

    // 72 weights (8 ch x 9 taps) = 288B contiguous, 16B aligned
    float wt[72];
    const float* cwp = &cw[c0 * 9];
#pragma unroll
    for (int i = 0; i < 18; ++i) {
        float4 v = *(const float4*)(cwp + i * 4);
        wt[i * 4 + 0] = v.x; wt[i * 4 + 1] = v.y;
        wt[i * 4 + 2] = v.z; wt[i * 4 + 3] = v.w;
    }
    float acc[8];
#pragma unroll
    for (int j = 0; j < 8; ++j) acc[j] = cb[c0 + j];

#pragma unroll
    for (int dh = -1; dh <= 1; ++dh) {
        int hh = h + dh;
        if (hh < 0 || hh >= H_SZ) continue;
#pragma unroll
        for (int dw = -1; dw <= 1; ++dw) {
            int ww = w + dw;
            if (ww < 0 || ww >= W_SZ) continue;
            int tap = (dh + 1) * 3 + (dw + 1);
            short8 xv = *(const short8*)&xzb[(size_t)((b * H_SZ + hh) * W_SZ + ww) * CIN + c0];
#pragma unroll
            for (int j = 0; j < 8; ++j)
                acc[j] = fmaf(b2f((ushort)xv[j]), wt[j * 9 + tap], acc[j]);
        }
    }

    float s[8];
#pragma unroll
    for (int j = 0; j < 8; ++j)
        s[j] = acc[j] * __builtin_amdgcn_rcpf(1.f + __expf(-acc[j]));   // SiLU

    int k = c0 / DI, d = c0 % DI;      // all 8 channels in same k (192 % 8 == 0)
    int lrow = h * W_SZ + w;
    int lcol = w * H_SZ + h;
    int l;
    if      (k == 0) l = lrow;
    else if (k == 1) l = lcol;
    else if (k == 2) l = L_SZ - 1 - lrow;
    else             l = L_SZ - 1 - lcol;
    float4 lo = {s[0], s[1], s[2], s[3]}, hi = {s[4], s[5], s[6], s[7]};
    *(short8*)&xsb[(size_t)((b * KG + k) * L_SZ + l) * DI + d] = f2b8(lo, hi);
}

// ---------------------------------------------------------------------------
// MFMA fused x-projection + dt-projection (32-token tiles, 384 threads).
// ---------------------------------------------------------------------------
__global__ __launch_bounds__(384) void xproj_dt_mfma(
        const ushort* __restrict__ xsb, const float* __restrict__ xpw,
        const float* __restrict__ dtw, const float* __restrict__ dtb,
        float* __restrict__ xdbl, ushort* __restrict__ dts_b) {
    __shared__ ushort Ws[48][200];
    __shared__ ushort Wd[192][40];
    __shared__ ushort dsh[32][40];

    const int tid  = threadIdx.x;
    const int lane = tid & 63;
    const int wave = tid >> 6;        // 0..5
    const int bm = blockIdx.x * 32;
    const int bk = blockIdx.y;
    const int k  = bk & 3;
    const int frow = lane & 15;
    const int fk   = (lane >> 4) * 8;
    const int orow = (lane >> 4) * 4;
    const int rg = wave & 1;
    const int cg = wave >> 1;

#pragma unroll
    for (int i = 0; i < 6; ++i) {
        int idx = tid + i * 384;
        int row = idx / 48, g = idx % 48;
        ushort4 u = {0, 0, 0, 0};
        if (row < XD) {
            float4 v = *(const float4*)&xpw[((size_t)(k * XD) + row) * 192 + g * 4];
            u.x = f2b(v.x); u.y = f2b(v.y); u.z = f2b(v.z); u.w = f2b(v.w);
        }
        *(ushort4*)&Ws[row][g * 4] = u;
    }
#pragma unroll
    for (int i = 0; i < 3; ++i) {
        int idx = tid + i * 384;
        if (idx < 960) {
            float4 z = {0.f, 0.f, 0.f, 0.f};
            *(float4*)&Wd[idx / 5][(idx % 5) * 8] = z;
        } else if (idx < 1120) {
            int j = idx - 960;
            float4 z = {0.f, 0.f, 0.f, 0.f};
            *(float4*)&dsh[j / 5][(j % 5) * 8] = z;
        }
    }
    __syncthreads();

#pragma unroll
    for (int i = 0; i < 6; ++i) {
        int idx = tid + i * 384;
        int row = idx / RR, c = idx % RR;
        Wd[row][c] = f2b(dtw[((size_t)(k * DI) + row) * RR + c]);
    }

    f32x4 acc1 = {};
    const ushort* arow = &xsb[(size_t)(bk * L_SZ + bm + rg * 16 + frow) * DI];
#pragma unroll
    for (int k0 = 0; k0 < 192; k0 += 32) {
        short8 af = *(const short8*)&arow[k0 + fk];
        short8 bv = *(const short8*)&Ws[cg * 16 + frow][k0 + fk];
        acc1 = __builtin_amdgcn_mfma_f32_16x16x32_bf16(af, bv, acc1, 0, 0, 0);
    }

    {
        int col = cg * 16 + frow;
#pragma unroll
        for (int r = 0; r < 4; ++r) {
            float v = acc1[r];
            int row = rg * 16 + orow + r;
            if (col >= RR && col < XD)
                xdbl[(size_t)(bk * L_SZ + bm + row) * XD + col] = v;
            if (cg == 0 && col < RR)
                dsh[row][col] = f2b(v);
        }
    }
    __syncthreads();

#pragma unroll
    for (int t = 0; t < 2; ++t) {
        int d = (wave * 2 + t) * 16 + frow;
        short8 bv = *(const short8*)&Wd[d][fk];
        float bias = dtb[k * DI + d];
#pragma unroll
        for (int rg2 = 0; rg2 < 2; ++rg2) {
            short8 af2 = *(const short8*)&dsh[rg2 * 16 + frow][fk];
            f32x4 a2 = {};
            a2 = __builtin_amdgcn_mfma_f32_16x16x32_bf16(af2, bv, a2, 0, 0, 0);
#pragma unroll
            for (int r = 0; r < 4; ++r) {
                float a = a2[r] + bias;
                float sp = fmaxf(a, 0.f) + __logf(1.f + __expf(-fabsf(a)));
                dts_b[(size_t)(bk * L_SZ + bm + rg2 * 16 + orow + r) * DI + d] = f2b(sp);
            }
        }
    }
}

// ---------------------------------------------------------------------------
// Scan pass A: per (bk, chunk, d, n) E = prod(e_l), S = local scan. CL=16.
// Fast path (A[n] == -(n+1)): E is fully determined by P = prod(exp(-dt)) ->
// write ONE scalar P per (chunk,d) instead of 16 E floats (Pbuf).
// Slow path: write full Ebuf + sentinel Pbuf = -1.
// ---------------------------------------------------------------------------
__global__ __launch_bounds__(192) void scan_passA(
        const ushort* __restrict__ dts_b, const ushort* __restrict__ xsb,
        const float* __restrict__ xdbl, const float* __restrict__ A_logs,
        float* __restrict__ Ebuf, float* __restrict__ Sbuf,
        float* __restrict__ Pbuf) {
    int blk = blockIdx.x;
    int bk = blk / NC, ch = blk % NC;
    int d = threadIdx.x, k = bk % KG;
    int l0 = ch * CL;

    __shared__ float bsh[CL][NS];
    for (int t = threadIdx.x; t < CL * NS; t += 192) {
        int l = t / NS, n = t % NS;
        bsh[l][n] = xdbl[(size_t)(bk * L_SZ + l0 + l) * XD + RR + n];
    }
    __syncthreads();

    float Aa[NS], S[NS];
    const float* ar = &A_logs[(size_t)(k * DI + d) * NS];
    bool fast = true;
#pragma unroll
    for (int n = 0; n < NS; ++n) {
        Aa[n] = -__expf(ar[n]);
        S[n] = 0.f;
        fast = fast && (fabsf(Aa[n] + (float)(n + 1)) < 1e-4f * (n + 1));
    }

    float* sp = &Sbuf[(size_t)((bk * NC + ch) * DI + d) * NS];
    if (fast) {
        float P = 1.f;
#pragma unroll
        for (int l = 0; l < CL; ++l) {
            float dt = b2f(dts_b[(size_t)(bk * L_SZ + l0 + l) * DI + d]);
            float u  = b2f(xsb [(size_t)(bk * L_SZ + l0 + l) * DI + d]);
            float du = dt * u;
            float4 b0 = *(const float4*)&bsh[l][0];
            float4 b1 = *(const float4*)&bsh[l][4];
            float4 b2 = *(const float4*)&bsh[l][8];
            float4 b3 = *(const float4*)&bsh[l][12];
            float Bv[NS] = {b0.x,b0.y,b0.z,b0.w, b1.x,b1.y,b1.z,b1.w,
                            b2.x,b2.y,b2.z,b2.w, b3.x,b3.y,b3.z,b3.w};
            float e1 = __expf(-dt);
            P *= e1;
            float e = e1;
            S[0] = fmaf(S[0], e, du * Bv[0]);
#pragma unroll
            for (int n = 1; n < NS; ++n) {
                e *= e1;
                S[n] = fmaf(S[n], e, du * Bv[n]);
            }
        }
        Pbuf[(size_t)(bk * NC + ch) * DI + d] = P;
#pragma unroll
        for (int q = 0; q < 4; ++q) {
            float4 v = {S[q*4], S[q*4+1], S[q*4+2], S[q*4+3]};
            *(float4*)&sp[q * 4] = v;
        }
    } else {
        float E[NS];
#pragma unroll
        for (int n = 0; n < NS; ++n) E[n] = 1.f;
#pragma unroll 8
        for (int l = 0; l < CL; ++l) {
            float dt = b2f(dts_b[(size_t)(bk * L_SZ + l0 + l) * DI + d]);
            float u  = b2f(xsb [(size_t)(bk * L_SZ + l0 + l) * DI + d]);
            float du = dt * u;
            float4 b0 = *(const float4*)&bsh[l][0];
            float4 b1 = *(const float4*)&bsh[l][4];
            float4 b2 = *(const float4*)&bsh[l][8];
            float4 b3 = *(const float4*)&bsh[l][12];
            float Bv[NS] = {b0.x,b0.y,b0.z,b0.w, b1.x,b1.y,b1.z,b1.w,
                            b2.x,b2.y,b2.z,b2.w, b3.x,b3.y,b3.z,b3.w};
#pragma unroll
            for (int n = 0; n < NS; ++n) {
                float e = __expf(dt * Aa[n]);
                E[n] *= e;
                S[n] = fmaf(S[n], e, du * Bv[n]);
            }
        }
        Pbuf[(size_t)(bk * NC + ch) * DI + d] = -1.f;
        float* ep = &Ebuf[(size_t)((bk * NC + ch) * DI + d) * NS];
#pragma unroll
        for (int q = 0; q < 4; ++q) {
            float4 ve = {E[q*4], E[q*4+1], E[q*4+2], E[q*4+3]};
            float4 vs = {S[q*4], S[q*4+1], S[q*4+2], S[q*4+3]};
            *(float4*)&ep[q * 4] = ve;
            *(float4*)&sp[q * 4] = vs;
        }
    }
}

// ---------------------------------------------------------------------------
// Scan pass B v3: chunk prefix, pipelined depth 8, fast path reconstructs
// E[n] = P^(n+1) from the scalar Pbuf (halves load stream, no Ebuf reads).
// 96 blocks x 64 threads. NC = 144 = 9 * 16.
// ---------------------------------------------------------------------------
__global__ __launch_bounds__(64) void scan_passB(
        const float* __restrict__ Ebuf, const float* __restrict__ Sbuf,
        const float* __restrict__ Pbuf, float* __restrict__ Hstart) {
    constexpr int P = 8;
    int t = blockIdx.x * 64 + threadIdx.x;        // 6144 threads
    int bk = t / (DI * 4);
    int dn = (t % (DI * 4)) * 4;                  // flat d*NS + n0
    int d  = dn >> 4;
    int n0 = dn & 15;
    const size_t stride = (size_t)DI * NS;
    size_t off  = (size_t)(bk * NC) * stride + dn;
    const float* pb = &Pbuf[(size_t)(bk * NC) * DI + d];

    float4 h = {0.f, 0.f, 0.f, 0.f};
    bool fastu = (pb[0] >= 0.f);

    if (fastu) {
        float  pA[P], pB[P];
        float4 sA[P], sB[P];
        size_t offL = off;
        int    cP   = 0;
#pragma unroll
        for (int j = 0; j < P; ++j) {
            pA[j] = pb[(size_t)(cP + j) * DI];
            sA[j] = *(const float4*)&Sbuf[offL + (size_t)j * stride];
        }
        offL += (size_t)P * stride; cP += P;

        for (int c = 0; c < NC; c += 2 * P) {
#pragma unroll
            for (int j = 0; j < P; ++j) {
                pB[j] = pb[(size_t)(cP + j) * DI];
                sB[j] = *(const float4*)&Sbuf[offL + (size_t)j * stride];
            }
            offL += (size_t)P * stride; cP += P;

#pragma unroll
            for (int j = 0; j < P; ++j) {
                *(float4*)&Hstart[off + (size_t)j * stride] = h;
                float Pv = pA[j];
                float P2 = Pv * Pv, P3 = P2 * Pv;
                float P4 = P2 * P2, P8 = P4 * P4;
                float base = Pv * ((n0 & 4) ? P4 : 1.f) * ((n0 & 8) ? P8 : 1.f);
                h.x = fmaf(base,      h.x, sA[j].x);
                h.y = fmaf(base * Pv, h.y, sA[j].y);
                h.z = fmaf(base * P2, h.z, sA[j].z);
                h.w = fmaf(base * P3, h.w, sA[j].w);
            }
            off += (size_t)P * stride;

            if (c + 2 * P < NC) {
#pragma unroll
                for (int j = 0; j < P; ++j) {
                    pA[j] = pb[(size_t)(cP + j) * DI];
                    sA[j] = *(const float4*)&Sbuf[offL + (size_t)j * stride];
                }
            }
            offL += (size_t)P * stride; cP += P;

#pragma unroll
            for (int j = 0; j < P; ++j) {
                *(float4*)&Hstart[off + (size_t)j * stride] = h;
                float Pv = pB[j];
                float P2 = Pv * Pv, P3 = P2 * Pv;
                float P4 = P2 * P2, P8 = P4 * P4;
                float base = Pv * ((n0 & 4) ? P4 : 1.f) * ((n0 & 8) ? P8 : 1.f);
                h.x = fmaf(base,      h.x, sB[j].x);
                h.y = fmaf(base * Pv, h.y, sB[j].y);
                h.z = fmaf(base * P2, h.z, sB[j].z);
                h.w = fmaf(base * P3, h.w, sB[j].w);
            }
            off += (size_t)P * stride;
        }
    } else {
        float4 eA[P], sA[P], eB[P], sB[P];
        size_t offL = off;
#pragma unroll
        for (int j = 0; j < P; ++j) {
            eA[j] = *(const float4*)&Ebuf[offL + (size_t)j * stride];
            sA[j] = *(const float4*)&Sbuf[offL + (size_t)j * stride];
        }
        offL += (size_t)P * stride;

        for (int c = 0; c < NC; c += 2 * P) {
#pragma unroll
            for (int j = 0; j < P; ++j) {
                eB[j] = *(const float4*)&Ebuf[offL + (size_t)j * stride];
                sB[j] = *(const float4*)&Sbuf[offL + (size_t)j * stride];
            }
            offL += (size_t)P * stride;

#pragma unroll
            for (int j = 0; j < P; ++j) {
                *(float4*)&Hstart[off + (size_t)j * stride] = h;
                h.x = fmaf(eA[j].x, h.x, sA[j].x);
                h.y = fmaf(eA[j].y, h.y, sA[j].y);
                h.z = fmaf(eA[j].z, h.z, sA[j].z);
                h.w = fmaf(eA[j].w, h.w, sA[j].w);
            }
            off += (size_t)P * stride;

            if (c + 2 * P < NC) {
#pragma unroll
                for (int j = 0; j < P; ++j) {
                    eA[j] = *(const float4*)&Ebuf[offL + (size_t)j * stride];
                    sA[j] = *(const float4*)&Sbuf[offL + (size_t)j * stride];
                }
            }
            offL += (size_t)P * stride;

#pragma unroll
            for (int j = 0; j < P; ++j) {
                *(float4*)&Hstart[off + (size_t)j * stride] = h;
                h.x = fmaf(eB[j].x, h.x, sB[j].x);
                h.y = fmaf(eB[j].y, h.y, sB[j].y);
                h.z = fmaf(eB[j].z, h.z, sB[j].z);
                h.w = fmaf(eB[j].w, h.w, sB[j].w);
            }
            off += (size_t)P * stride;
        }
    }
}

// ---------------------------------------------------------------------------
// Scan pass C: replay chunk with true h_start, emit y (bf16 spatial scatter).
// ---------------------------------------------------------------------------
__global__ __launch_bounds__(192) void scan_passC(
        const ushort* __restrict__ dts_b, const ushort* __restrict__ xsb,
        const float* __restrict__ xdbl, const float* __restrict__ A_logs,
        const float* __restrict__ Hstart, const float* __restrict__ Ds,
        ushort* __restrict__ ypre_b) {
    int blk = blockIdx.x;
    int bk = blk / NC, ch = blk % NC;
    int d = threadIdx.x, k = bk % KG, b = bk / KG;
    int l0 = ch * CL;

    __shared__ float bsh[CL][NS];
    __shared__ float csh[CL][NS];
    for (int t = threadIdx.x; t < CL * NS; t += 192) {
        int l = t / NS, n = t % NS;
        const float* row = &xdbl[(size_t)(bk * L_SZ + l0 + l) * XD];
        bsh[l][n] = row[RR + n];
        csh[l][n] = row[RR + NS + n];
    }
    __syncthreads();

    float Aa[NS], h[NS];
    const float* ar = &A_logs[(size_t)(k * DI + d) * NS];
    const float* hp = &Hstart[(size_t)((bk * NC + ch) * DI + d) * NS];
    bool fast = true;
#pragma unroll
    for (int n = 0; n < NS; ++n) {
        Aa[n] = -__expf(ar[n]);
        h[n] = hp[n];
        fast = fast && (fabsf(Aa[n] + (float)(n + 1)) < 1e-4f * (n + 1));
    }
    float Dd = Ds[k * DI + d];

#pragma unroll 8
    for (int l = 0; l < CL; ++l) {
        float dt = b2f(dts_b[(size_t)(bk * L_SZ + l0 + l) * DI + d]);
        float u  = b2f(xsb [(size_t)(bk * L_SZ + l0 + l) * DI + d]);
        float du = dt * u;
        float4 b0 = *(const float4*)&bsh[l][0];
        float4 b1 = *(const float4*)&bsh[l][4];
        float4 b2 = *(const float4*)&bsh[l][8];
        float4 b3 = *(const float4*)&bsh[l][12];
        float Bv[NS] = {b0.x,b0.y,b0.z,b0.w, b1.x,b1.y,b1.z,b1.w,
                        b2.x,b2.y,b2.z,b2.w, b3.x,b3.y,b3.z,b3.w};
        float4 c0 = *(const float4*)&csh[l][0];
        float4 c1 = *(const float4*)&csh[l][4];
        float4 c2 = *(const float4*)&csh[l][8];
        float4 c3 = *(const float4*)&csh[l][12];
        float Cv[NS] = {c0.x,c0.y,c0.z,c0.w, c1.x,c1.y,c1.z,c1.w,
                        c2.x,c2.y,c2.z,c2.w, c3.x,c3.y,c3.z,c3.w};
        float p[NS];
        if (fast) {
            float e1 = __expf(-dt);
            float e = e1;
            h[0] = fmaf(h[0], e, du * Bv[0]);
            p[0] = h[0] * Cv[0];
#pragma unroll
            for (int n = 1; n < NS; ++n) {
                e *= e1;
                h[n] = fmaf(h[n], e, du * Bv[n]);
                p[n] = h[n] * Cv[n];
            }
        } else {
#pragma unroll
            for (int n = 0; n < NS; ++n) {
                float e = __expf(dt * Aa[n]);
                h[n] = fmaf(h[n], e, du * Bv[n]);
                p[n] = h[n] * Cv[n];
            }
        }
#pragma unroll
        for (int s = 8; s >= 1; s >>= 1)
#pragma unroll
            for (int n = 0; n < 8; ++n)
                if (n < s) p[n] = p[n] + p[n + s];
        float y = fmaf(Dd, u, p[0]);

        int lg = l0 + l;
        int pos;
        if      (k == 0) pos = lg;
        else if (k == 1) pos = (lg % H_SZ) * W_SZ + (lg / H_SZ);
        else if (k == 2) pos = L_SZ - 1 - lg;
        else { int j = L_SZ - 1 - lg; pos = (j % H_SZ) * W_SZ + (j / H_SZ); }
        ypre_b[(size_t)(b * L_SZ + pos) * CIN + k * DI + d] = f2b(y);
    }
}

// ---------------------------------------------------------------------------
// LayerNorm over CIN=768; bf16 in, bf16 out (stats in fp32).
// ---------------------------------------------------------------------------
__global__ __launch_bounds__(256) void layernorm_bf16(
        const ushort* __restrict__ y, ushort* __restrict__ yb,
        const float* __restrict__ w, const float* __restrict__ bg) {
    int wave = threadIdx.x >> 6, lane = threadIdx.x & 63;
    int tok = blockIdx.x * 4 + wave;
    const ushort* row = &y[(size_t)tok * CIN];
    ushort* rowo = &yb[(size_t)tok * CIN];
    float v[12];
    float s = 0.f;
#pragma unroll
    for (int i = 0; i < 12; ++i) { v[i] = b2f(row[lane + i * 64]); s += v[i]; }
#pragma unroll
    for (int off = 32; off >= 1; off >>= 1) s += __shfl_xor(s, off, 64);
    float mu = s * (1.f / CIN);
    float s2 = 0.f;
#pragma unroll
    for (int i = 0; i < 12; ++i) { float t = v[i] - mu; s2 += t * t; }
#pragma unroll
    for (int off = 32; off >= 1; off >>= 1) s2 += __shfl_xor(s2, off, 64);
    float rstd = rsqrtf(s2 * (1.f / CIN) + 1e-5f);
#pragma unroll
    for (int i = 0; i < 12; ++i)
        rowo[lane + i * 64] =
            f2b((v[i] - mu) * rstd * w[lane + i * 64] + bg[lane + i * 64]);
}

// ---------------------------------------------------------------------------
extern "C" void kernel_launch(void* const* d_in, const int* in_sizes, int n_in,
                              void* d_out, int out_size, void* d_ws, size_t ws_size,
                              hipStream_t stream) {
    const float* x    = (const float*)d_in[0];
    const float* inw  = (const float*)d_in[1];
    const float* cw   = (const float*)d_in[2];
    const float* cb   = (const float*)d_in[3];
    const float* xpw  = (const float*)d_in[4];
    const float* dtw  = (const float*)d_in[5];
    const float* dtb  = (const float*)d_in[6];
    const float* alog = (const float*)d_in[7];
    const float* Dsp  = (const float*)d_in[8];
    const float* lnw  = (const float*)d_in[9];
    const float* lnb  = (const float*)d_in[10];
    const float* outw = (const float*)d_in[11];
    float* out = (float*)d_out;

    float* ws = (float*)d_ws;
    const size_t SZ_BIG = (size_t)MTOK * CIN;            // 3,538,944
    const size_t SCAN_SL = (size_t)8 * NC * DI * NS;     // 3,538,944 (CL=16)
    float* xz    = ws;                                   // bf16 in-proj out; later ypre_b
    float* xsbf  = xz  + SZ_BIG;                         // bf16 xs (float slots)
    float* dts   = xsbf + SZ_BIG / 2;                    // bf16 dts; later ynrm_b
    float* xdbl  = dts + SZ_BIG;                         // (8,L,44) fp32
    float* Ebuf  = xdbl + (size_t)8 * L_SZ * XD;
    float* Sbuf  = Ebuf + SCAN_SL;
    float* Hst   = Sbuf + SCAN_SL;
    float* Pbuf  = Hst + SCAN_SL;                        // 8*NC*DI fp32
    // overlays (strictly sequential producer/consumer):
    ushort* xzb    = (ushort*)xz;     // gemm1 out (bf16) -> conv in
    ushort* xsb    = (ushort*)xsbf;   // conv -> xproj + scans
    ushort* dtsb   = (ushort*)dts;    // xproj -> scans
    ushort* ypre_b = (ushort*)xz;     // scanC out -> LN in (xzb dead after conv)
    ushort* ynrm_b = (ushort*)dts;    // LN out -> out-proj (dtsb dead after scanC)

    // 1. in-proj GEMM (bf16 MFMA, inline fp32->bf16 A-cast, bf16 C out)
    gemm_tn64<128, false, true><<<dim3(CIN / 64, MTOK / 128), 256, 0, stream>>>(
        x, inw, xzb, MTOK, CIN, 384);
    // 2. depthwise conv + SiLU + scatter (8 ch/thread, vectorized)
    conv_silu_scatter<<<(B_SZ * H_SZ * W_SZ * 96) / 256, 256, 0, stream>>>(xzb, cw, cb, xsb);
    // 3. fused MFMA x-projection + dt-projection (32-token tiles, 576 blocks)
    xproj_dt_mfma<<<dim3(L_SZ / 32, 8), 384, 0, stream>>>(xsb, xpw, dtw, dtb, xdbl, dtsb);
    // 4-6. chunked selective scan (CL=16, Pbuf-compressed E)
    scan_passA<<<8 * NC, 192, 0, stream>>>(dtsb, xsb, xdbl, alog, Ebuf, Sbuf, Pbuf);
    scan_passB<<<(8 * DI * 4) / 64, 64, 0, stream>>>(Ebuf, Sbuf, Pbuf, Hst);
    scan_passC<<<8 * NC, 192, 0, stream>>>(dtsb, xsb, xdbl, alog, Hst, Dsp, ypre_b);
    // 7. LayerNorm: bf16 in, bf16 out
    layernorm_bf16<<<MTOK / 4, 256, 0, stream>>>(ypre_b, ynrm_b, lnw, lnb);
    // 8. out-proj GEMM (bf16 A, inline-cast B, fp32 out)
    gemm_tn64<64, true, false><<<dim3(384 / 64, MTOK / 64), 256, 0, stream>>>(
        ynrm_b, outw, out, MTOK, 384, CIN);
}

// Round 7
// 178.508 us; speedup vs baseline: 1.3697x; 1.0343x over previous
//
#include <hip/hip_runtime.h>
#include <hip/hip_bf16.h>

#define B_SZ   2
#define H_SZ   48
#define W_SZ   48
#define L_SZ   2304          // H*W
#define CIN    768           // C_INNER
#define KG     4
#define DI     192           // D_IN (channels per direction)
#define NS     16            // N_STATE
#define RR     12            // R_RANK
#define XD     44            // RR + 2*NS
#define MTOK   4608          // B*L
#define CL     16            // scan chunk length
#define NC     144           // L / CL

typedef __attribute__((ext_vector_type(8))) short short8;
typedef __attribute__((ext_vector_type(4))) float f32x4;

__device__ inline ushort f2b(float f) {
    uint u = __builtin_bit_cast(uint, f);
    u = (u + 0x7FFF + ((u >> 16) & 1)) >> 16;   // RNE to bf16
    return (ushort)u;
}
__device__ inline float b2f(ushort b) {
    uint u = ((uint)b) << 16;
    return __builtin_bit_cast(float, u);
}
__device__ inline short8 f2b8(float4 a, float4 b) {
    short8 r;
    r[0] = (short)f2b(a.x); r[1] = (short)f2b(a.y);
    r[2] = (short)f2b(a.z); r[3] = (short)f2b(a.w);
    r[4] = (short)f2b(b.x); r[5] = (short)f2b(b.y);
    r[6] = (short)f2b(b.z); r[7] = (short)f2b(b.w);
    return r;
}

// ---------------------------------------------------------------------------
// Software grid barrier (device scope). Requires all blocks co-resident —
// guaranteed at launch time via occupancy query + fallback path.
// bar[0] = arrive counter, bar[1] = generation. Zeroed via hipMemsetAsync.
// ---------------------------------------------------------------------------
__device__ inline void gridbar(uint* bar, uint nb) {
    __syncthreads();
    if (threadIdx.x == 0) {
        uint g = __hip_atomic_load(&bar[1], __ATOMIC_RELAXED, __HIP_MEMORY_SCOPE_AGENT);
        uint a = __hip_atomic_fetch_add(&bar[0], 1u, __ATOMIC_ACQ_REL, __HIP_MEMORY_SCOPE_AGENT);
        if (a == nb - 1u) {
            __hip_atomic_store(&bar[0], 0u, __ATOMIC_RELAXED, __HIP_MEMORY_SCOPE_AGENT);
            __hip_atomic_store(&bar[1], g + 1u, __ATOMIC_RELEASE, __HIP_MEMORY_SCOPE_AGENT);
        } else {
            while (__hip_atomic_load(&bar[1], __ATOMIC_ACQUIRE, __HIP_MEMORY_SCOPE_AGENT) == g) {
                __builtin_amdgcn_s_sleep(8);
            }
        }
    }
    __syncthreads();
}

// ---------------------------------------------------------------------------
// MFMA GEMM, TN=64 column tiles, K-step 64 (half the barriers of K-step 32).
// C[M,N] = A[M,K] * Bw[N,K]^T
// ---------------------------------------------------------------------------
template<int TM, bool ABF, bool CBF>
__global__ __launch_bounds__(256) void gemm_tn64(
        const void* __restrict__ Av, const float* __restrict__ Bw,
        void* __restrict__ Cv, int M, int N, int K) {
    __shared__ ushort As[TM][72];
    __shared__ ushort Bs[64][72];
    const int tid  = threadIdx.x;
    const int lane = tid & 63;
    const int wave = tid >> 6;
    constexpr int MF = TM / 64;
    const int wrow = wave * (MF * 16);
    const int bm = blockIdx.y * TM, bn = blockIdx.x * 64;
    const int frow = lane & 15;
    const int fk   = (lane >> 4) * 8;
    const int orow = (lane >> 4) * 4;

    f32x4 acc[MF][4] = {};

    for (int k0 = 0; k0 < K; k0 += 64) {
        short8 aval[2 * MF];
#pragma unroll
        for (int i = 0; i < 2 * MF; ++i) {
            int idx = tid + i * 256;
            int row = idx >> 3, q = idx & 7;
            if (ABF) {
                aval[i] = *(const short8*)&((const ushort*)Av)[(size_t)(bm + row) * K + k0 + q * 8];
            } else {
                const float* ap = &((const float*)Av)[(size_t)(bm + row) * K + k0 + q * 8];
                aval[i] = f2b8(*(const float4*)ap, *(const float4*)(ap + 4));
            }
        }
        short8 bval[2];
#pragma unroll
        for (int i = 0; i < 2; ++i) {
            int idx = tid + i * 256;
            int row = idx >> 3, q = idx & 7;
            const float* bp = &Bw[(size_t)(bn + row) * K + k0 + q * 8];
            bval[i] = f2b8(*(const float4*)bp, *(const float4*)(bp + 4));
        }

        __syncthreads();
#pragma unroll
        for (int i = 0; i < 2 * MF; ++i) {
            int idx = tid + i * 256;
            *(short8*)&As[idx >> 3][(idx & 7) * 8] = aval[i];
        }
#pragma unroll
        for (int i = 0; i < 2; ++i) {
            int idx = tid + i * 256;
            *(short8*)&Bs[idx >> 3][(idx & 7) * 8] = bval[i];
        }
        __syncthreads();

#pragma unroll
        for (int hf = 0; hf < 2; ++hf) {
            short8 af[MF], bf[4];
#pragma unroll
            for (int mi = 0; mi < MF; ++mi)
                af[mi] = *(const short8*)&As[wrow + mi * 16 + frow][hf * 32 + fk];
#pragma unroll
            for (int ni = 0; ni < 4; ++ni)
                bf[ni] = *(const short8*)&Bs[ni * 16 + frow][hf * 32 + fk];
#pragma unroll
            for (int mi = 0; mi < MF; ++mi)
#pragma unroll
                for (int ni = 0; ni < 4; ++ni)
                    acc[mi][ni] = __builtin_amdgcn_mfma_f32_16x16x32_bf16(
                                      af[mi], bf[ni], acc[mi][ni], 0, 0, 0);
        }
    }

#pragma unroll
    for (int mi = 0; mi < MF; ++mi) {
        int rbase = bm + wrow + mi * 16 + orow;
#pragma unroll
        for (int ni = 0; ni < 4; ++ni) {
            int col = bn + ni * 16 + frow;
#pragma unroll
            for (int r = 0; r < 4; ++r) {
                if (CBF)
                    ((ushort*)Cv)[(size_t)(rbase + r) * N + col] = f2b(acc[mi][ni][r]);
                else
                    ((float*)Cv)[(size_t)(rbase + r) * N + col] = acc[mi][ni][r];
            }
        }
    }
}

// ---------------------------------------------------------------------------
// Depthwise 3x3 conv + bias + SiLU, 8 channels/thread, vectorized.
// ---------------------------------------------------------------------------
__global__ __launch_bounds__(256) void conv_silu_scatter(
        const ushort* __restrict__ xzb, const float* __restrict__ cw,
        const float* __restrict__ cb, ushort* __restrict__ xsb) {
    int g = blockIdx.x * 256 + threadIdx.x;     // 442368 total
    int c8 = g % 96;
    int pos = g / 96;
    int w = pos % W_SZ;
    int h = (pos / W_SZ) % H_SZ;
    int b = pos / (W_SZ * H_SZ);
    int c0 = c8 * 8;

    float wt[72];
    const float* cwp = &cw[c0 * 9];
#pragma unroll
    for (int i = 0; i < 18; ++i) {
        float4 v = *(const float4*)(cwp + i * 4);
        wt[i * 4 + 0] = v.x; wt[i * 4 + 1] = v.y;
        wt[i * 4 + 2] = v.z; wt[i * 4 + 3] = v.w;
    }
    float acc[8];
#pragma unroll
    for (int j = 0; j < 8; ++j) acc[j] = cb[c0 + j];

#pragma unroll
    for (int dh = -1; dh <= 1; ++dh) {
        int hh = h + dh;
        if (hh < 0 || hh >= H_SZ) continue;
#pragma unroll
        for (int dw = -1; dw <= 1; ++dw) {
            int ww = w + dw;
            if (ww < 0 || ww >= W_SZ) continue;
            int tap = (dh + 1) * 3 + (dw + 1);
            short8 xv = *(const short8*)&xzb[(size_t)((b * H_SZ + hh) * W_SZ + ww) * CIN + c0];
#pragma unroll
            for (int j = 0; j < 8; ++j)
                acc[j] = fmaf(b2f((ushort)xv[j]), wt[j * 9 + tap], acc[j]);
        }
    }

    float s[8];
#pragma unroll
    for (int j = 0; j < 8; ++j)
        s[j] = acc[j] * __builtin_amdgcn_rcpf(1.f + __expf(-acc[j]));   // SiLU

    int k = c0 / DI, d = c0 % DI;
    int lrow = h * W_SZ + w;
    int lcol = w * H_SZ + h;
    int l;
    if      (k == 0) l = lrow;
    else if (k == 1) l = lcol;
    else if (k == 2) l = L_SZ - 1 - lrow;
    else             l = L_SZ - 1 - lcol;
    float4 lo = {s[0], s[1], s[2], s[3]}, hi = {s[4], s[5], s[6], s[7]};
    *(short8*)&xsb[(size_t)((b * KG + k) * L_SZ + l) * DI + d] = f2b8(lo, hi);
}

// ---------------------------------------------------------------------------
// MFMA fused x-projection + dt-projection (32-token tiles, 384 threads).
// ---------------------------------------------------------------------------
__global__ __launch_bounds__(384) void xproj_dt_mfma(
        const ushort* __restrict__ xsb, const float* __restrict__ xpw,
        const float* __restrict__ dtw, const float* __restrict__ dtb,
        float* __restrict__ xdbl, ushort* __restrict__ dts_b) {
    __shared__ ushort Ws[48][200];
    __shared__ ushort Wd[192][40];
    __shared__ ushort dsh[32][40];

    const int tid  = threadIdx.x;
    const int lane = tid & 63;
    const int wave = tid >> 6;        // 0..5
    const int bm = blockIdx.x * 32;
    const int bk = blockIdx.y;
    const int k  = bk & 3;
    const int frow = lane & 15;
    const int fk   = (lane >> 4) * 8;
    const int orow = (lane >> 4) * 4;
    const int rg = wave & 1;
    const int cg = wave >> 1;

#pragma unroll
    for (int i = 0; i < 6; ++i) {
        int idx = tid + i * 384;
        int row = idx / 48, g = idx % 48;
        ushort4 u = {0, 0, 0, 0};
        if (row < XD) {
            float4 v = *(const float4*)&xpw[((size_t)(k * XD) + row) * 192 + g * 4];
            u.x = f2b(v.x); u.y = f2b(v.y); u.z = f2b(v.z); u.w = f2b(v.w);
        }
        *(ushort4*)&Ws[row][g * 4] = u;
    }
#pragma unroll
    for (int i = 0; i < 3; ++i) {
        int idx = tid + i * 384;
        if (idx < 960) {
            float4 z = {0.f, 0.f, 0.f, 0.f};
            *(float4*)&Wd[idx / 5][(idx % 5) * 8] = z;
        } else if (idx < 1120) {
            int j = idx - 960;
            float4 z = {0.f, 0.f, 0.f, 0.f};
            *(float4*)&dsh[j / 5][(j % 5) * 8] = z;
        }
    }
    __syncthreads();

#pragma unroll
    for (int i = 0; i < 6; ++i) {
        int idx = tid + i * 384;
        int row = idx / RR, c = idx % RR;
        Wd[row][c] = f2b(dtw[((size_t)(k * DI) + row) * RR + c]);
    }

    f32x4 acc1 = {};
    const ushort* arow = &xsb[(size_t)(bk * L_SZ + bm + rg * 16 + frow) * DI];
#pragma unroll
    for (int k0 = 0; k0 < 192; k0 += 32) {
        short8 af = *(const short8*)&arow[k0 + fk];
        short8 bv = *(const short8*)&Ws[cg * 16 + frow][k0 + fk];
        acc1 = __builtin_amdgcn_mfma_f32_16x16x32_bf16(af, bv, acc1, 0, 0, 0);
    }

    {
        int col = cg * 16 + frow;
#pragma unroll
        for (int r = 0; r < 4; ++r) {
            float v = acc1[r];
            int row = rg * 16 + orow + r;
            if (col >= RR && col < XD)
                xdbl[(size_t)(bk * L_SZ + bm + row) * XD + col] = v;
            if (cg == 0 && col < RR)
                dsh[row][col] = f2b(v);
        }
    }
    __syncthreads();

#pragma unroll
    for (int t = 0; t < 2; ++t) {
        int d = (wave * 2 + t) * 16 + frow;
        short8 bv = *(const short8*)&Wd[d][fk];
        float bias = dtb[k * DI + d];
#pragma unroll
        for (int rg2 = 0; rg2 < 2; ++rg2) {
            short8 af2 = *(const short8*)&dsh[rg2 * 16 + frow][fk];
            f32x4 a2 = {};
            a2 = __builtin_amdgcn_mfma_f32_16x16x32_bf16(af2, bv, a2, 0, 0, 0);
#pragma unroll
            for (int r = 0; r < 4; ++r) {
                float a = a2[r] + bias;
                float sp = fmaxf(a, 0.f) + __logf(1.f + __expf(-fabsf(a)));
                dts_b[(size_t)(bk * L_SZ + bm + rg2 * 16 + orow + r) * DI + d] = f2b(sp);
            }
        }
    }
}

// ---------------------------------------------------------------------------
// FUSED three-pass scan in ONE kernel via software grid barrier.
// Phase A/B/C bodies identical to the proven separate kernels; B/C-state LDS
// tiles staged once. 1152 blocks x 192 threads, co-residency checked by host.
// ---------------------------------------------------------------------------
__global__ __launch_bounds__(192, 4) void scan_fused(
        const ushort* __restrict__ dts_b, const ushort* __restrict__ xsb,
        const float* __restrict__ xdbl, const float* __restrict__ A_logs,
        float* __restrict__ Ebuf, float* __restrict__ Sbuf,
        float* __restrict__ Pbuf, float* __restrict__ Hstart,
        const float* __restrict__ Ds, ushort* __restrict__ ypre_b,
        uint* __restrict__ bar) {
    const int blk = blockIdx.x;
    const int bk = blk / NC, ch = blk % NC;
    const int d = threadIdx.x, k = bk % KG, b = bk / KG;
    const int l0 = ch * CL;

    __shared__ float bsh[CL][NS];
    __shared__ float csh[CL][NS];
    for (int t = threadIdx.x; t < CL * NS; t += 192) {
        int l = t / NS, n = t % NS;
        const float* row = &xdbl[(size_t)(bk * L_SZ + l0 + l) * XD];
        bsh[l][n] = row[RR + n];
        csh[l][n] = row[RR + NS + n];
    }
    __syncthreads();

    // ---------------- phase A: per-chunk E/S (Pbuf-compressed) ------------
    {
        float Aa[NS], S[NS];
        const float* ar = &A_logs[(size_t)(k * DI + d) * NS];
        bool fast = true;
#pragma unroll
        for (int n = 0; n < NS; ++n) {
            Aa[n] = -__expf(ar[n]);
            S[n] = 0.f;
            fast = fast && (fabsf(Aa[n] + (float)(n + 1)) < 1e-4f * (n + 1));
        }
        float* sp = &Sbuf[(size_t)((bk * NC + ch) * DI + d) * NS];
        if (fast) {
            float P = 1.f;
#pragma unroll
            for (int l = 0; l < CL; ++l) {
                float dt = b2f(dts_b[(size_t)(bk * L_SZ + l0 + l) * DI + d]);
                float u  = b2f(xsb [(size_t)(bk * L_SZ + l0 + l) * DI + d]);
                float du = dt * u;
                float4 b0 = *(const float4*)&bsh[l][0];
                float4 b1 = *(const float4*)&bsh[l][4];
                float4 b2 = *(const float4*)&bsh[l][8];
                float4 b3 = *(const float4*)&bsh[l][12];
                float Bv[NS] = {b0.x,b0.y,b0.z,b0.w, b1.x,b1.y,b1.z,b1.w,
                                b2.x,b2.y,b2.z,b2.w, b3.x,b3.y,b3.z,b3.w};
                float e1 = __expf(-dt);
                P *= e1;
                float e = e1;
                S[0] = fmaf(S[0], e, du * Bv[0]);
#pragma unroll
                for (int n = 1; n < NS; ++n) {
                    e *= e1;
                    S[n] = fmaf(S[n], e, du * Bv[n]);
                }
            }
            Pbuf[(size_t)(bk * NC + ch) * DI + d] = P;
#pragma unroll
            for (int q = 0; q < 4; ++q) {
                float4 v = {S[q*4], S[q*4+1], S[q*4+2], S[q*4+3]};
                *(float4*)&sp[q * 4] = v;
            }
        } else {
            float E[NS];
#pragma unroll
            for (int n = 0; n < NS; ++n) E[n] = 1.f;
#pragma unroll 8
            for (int l = 0; l < CL; ++l) {
                float dt = b2f(dts_b[(size_t)(bk * L_SZ + l0 + l) * DI + d]);
                float u  = b2f(xsb [(size_t)(bk * L_SZ + l0 + l) * DI + d]);
                float du = dt * u;
                float4 b0 = *(const float4*)&bsh[l][0];
                float4 b1 = *(const float4*)&bsh[l][4];
                float4 b2 = *(const float4*)&bsh[l][8];
                float4 b3 = *(const float4*)&bsh[l][12];
                float Bv[NS] = {b0.x,b0.y,b0.z,b0.w, b1.x,b1.y,b1.z,b1.w,
                                b2.x,b2.y,b2.z,b2.w, b3.x,b3.y,b3.z,b3.w};
#pragma unroll
                for (int n = 0; n < NS; ++n) {
                    float e = __expf(dt * Aa[n]);
                    E[n] *= e;
                    S[n] = fmaf(S[n], e, du * Bv[n]);
                }
            }
            Pbuf[(size_t)(bk * NC + ch) * DI + d] = -1.f;
            float* ep = &Ebuf[(size_t)((bk * NC + ch) * DI + d) * NS];
#pragma unroll
            for (int q = 0; q < 4; ++q) {
                float4 ve = {E[q*4], E[q*4+1], E[q*4+2], E[q*4+3]};
                float4 vs = {S[q*4], S[q*4+1], S[q*4+2], S[q*4+3]};
                *(float4*)&ep[q * 4] = ve;
                *(float4*)&sp[q * 4] = vs;
            }
        }
    }

    gridbar(bar, gridDim.x);

    // ---------------- phase B: chunk prefix (first 6144 threads) ----------
    {
        constexpr int P = 8;
        int t = blk * 192 + threadIdx.x;
        if (t < 8 * DI * 4) {
            int bkB = t / (DI * 4);
            int dn = (t % (DI * 4)) * 4;
            int dB = dn >> 4;
            int n0 = dn & 15;
            const size_t stride = (size_t)DI * NS;
            size_t off = (size_t)(bkB * NC) * stride + dn;
            const float* pb = &Pbuf[(size_t)(bkB * NC) * DI + dB];

            float4 h = {0.f, 0.f, 0.f, 0.f};
            bool fastu = (pb[0] >= 0.f);

            if (fastu) {
                float  pA[P], pB2[P];
                float4 sA[P], sB[P];
                size_t offL = off;
                int    cP   = 0;
#pragma unroll
                for (int j = 0; j < P; ++j) {
                    pA[j] = pb[(size_t)(cP + j) * DI];
                    sA[j] = *(const float4*)&Sbuf[offL + (size_t)j * stride];
                }
                offL += (size_t)P * stride; cP += P;

                for (int c = 0; c < NC; c += 2 * P) {
#pragma unroll
                    for (int j = 0; j < P; ++j) {
                        pB2[j] = pb[(size_t)(cP + j) * DI];
                        sB[j] = *(const float4*)&Sbuf[offL + (size_t)j * stride];
                    }
                    offL += (size_t)P * stride; cP += P;

#pragma unroll
                    for (int j = 0; j < P; ++j) {
                        *(float4*)&Hstart[off + (size_t)j * stride] = h;
                        float Pv = pA[j];
                        float P2 = Pv * Pv, P3 = P2 * Pv;
                        float P4 = P2 * P2, P8 = P4 * P4;
                        float base = Pv * ((n0 & 4) ? P4 : 1.f) * ((n0 & 8) ? P8 : 1.f);
                        h.x = fmaf(base,      h.x, sA[j].x);
                        h.y = fmaf(base * Pv, h.y, sA[j].y);
                        h.z = fmaf(base * P2, h.z, sA[j].z);
                        h.w = fmaf(base * P3, h.w, sA[j].w);
                    }
                    off += (size_t)P * stride;

                    if (c + 2 * P < NC) {
#pragma unroll
                        for (int j = 0; j < P; ++j) {
                            pA[j] = pb[(size_t)(cP + j) * DI];
                            sA[j] = *(const float4*)&Sbuf[offL + (size_t)j * stride];
                        }
                    }
                    offL += (size_t)P * stride; cP += P;

#pragma unroll
                    for (int j = 0; j < P; ++j) {
                        *(float4*)&Hstart[off + (size_t)j * stride] = h;
                        float Pv = pB2[j];
                        float P2 = Pv * Pv, P3 = P2 * Pv;
                        float P4 = P2 * P2, P8 = P4 * P4;
                        float base = Pv * ((n0 & 4) ? P4 : 1.f) * ((n0 & 8) ? P8 : 1.f);
                        h.x = fmaf(base,      h.x, sB[j].x);
                        h.y = fmaf(base * Pv, h.y, sB[j].y);
                        h.z = fmaf(base * P2, h.z, sB[j].z);
                        h.w = fmaf(base * P3, h.w, sB[j].w);
                    }
                    off += (size_t)P * stride;
                }
            } else {
                float4 eA[P], sA[P], eB[P], sB[P];
                size_t offL = off;
#pragma unroll
                for (int j = 0; j < P; ++j) {
                    eA[j] = *(const float4*)&Ebuf[offL + (size_t)j * stride];
                    sA[j] = *(const float4*)&Sbuf[offL + (size_t)j * stride];
                }
                offL += (size_t)P * stride;

                for (int c = 0; c < NC; c += 2 * P) {
#pragma unroll
                    for (int j = 0; j < P; ++j) {
                        eB[j] = *(const float4*)&Ebuf[offL + (size_t)j * stride];
                        sB[j] = *(const float4*)&Sbuf[offL + (size_t)j * stride];
                    }
                    offL += (size_t)P * stride;

#pragma unroll
                    for (int j = 0; j < P; ++j) {
                        *(float4*)&Hstart[off + (size_t)j * stride] = h;
                        h.x = fmaf(eA[j].x, h.x, sA[j].x);
                        h.y = fmaf(eA[j].y, h.y, sA[j].y);
                        h.z = fmaf(eA[j].z, h.z, sA[j].z);
                        h.w = fmaf(eA[j].w, h.w, sA[j].w);
                    }
                    off += (size_t)P * stride;

                    if (c + 2 * P < NC) {
#pragma unroll
                        for (int j = 0; j < P; ++j) {
                            eA[j] = *(const float4*)&Ebuf[offL + (size_t)j * stride];
                            sA[j] = *(const float4*)&Sbuf[offL + (size_t)j * stride];
                        }
                    }
                    offL += (size_t)P * stride;

#pragma unroll
                    for (int j = 0; j < P; ++j) {
                        *(float4*)&Hstart[off + (size_t)j * stride] = h;
                        h.x = fmaf(eB[j].x, h.x, sB[j].x);
                        h.y = fmaf(eB[j].y, h.y, sB[j].y);
                        h.z = fmaf(eB[j].z, h.z, sB[j].z);
                        h.w = fmaf(eB[j].w, h.w, sB[j].w);
                    }
                    off += (size_t)P * stride;
                }
            }
        }
    }

    gridbar(bar, gridDim.x);

    // ---------------- phase C: replay with true h_start, emit y -----------
    {
        float Aa[NS], h[NS];
        const float* ar = &A_logs[(size_t)(k * DI + d) * NS];
        const float* hp = &Hstart[(size_t)((bk * NC + ch) * DI + d) * NS];
        bool fast = true;
#pragma unroll
        for (int n = 0; n < NS; ++n) {
            Aa[n] = -__expf(ar[n]);
            h[n] = hp[n];
            fast = fast && (fabsf(Aa[n] + (float)(n + 1)) < 1e-4f * (n + 1));
        }
        float Dd = Ds[k * DI + d];

#pragma unroll 8
        for (int l = 0; l < CL; ++l) {
            float dt = b2f(dts_b[(size_t)(bk * L_SZ + l0 + l) * DI + d]);
            float u  = b2f(xsb [(size_t)(bk * L_SZ + l0 + l) * DI + d]);
            float du = dt * u;
            float4 b0 = *(const float4*)&bsh[l][0];
            float4 b1 = *(const float4*)&bsh[l][4];
            float4 b2 = *(const float4*)&bsh[l][8];
            float4 b3 = *(const float4*)&bsh[l][12];
            float Bv[NS] = {b0.x,b0.y,b0.z,b0.w, b1.x,b1.y,b1.z,b1.w,
                            b2.x,b2.y,b2.z,b2.w, b3.x,b3.y,b3.z,b3.w};
            float4 c0 = *(const float4*)&csh[l][0];
            float4 c1 = *(const float4*)&csh[l][4];
            float4 c2 = *(const float4*)&csh[l][8];
            float4 c3 = *(const float4*)&csh[l][12];
            float Cv[NS] = {c0.x,c0.y,c0.z,c0.w, c1.x,c1.y,c1.z,c1.w,
                            c2.x,c2.y,c2.z,c2.w, c3.x,c3.y,c3.z,c3.w};
            float p[NS];
            if (fast) {
                float e1 = __expf(-dt);
                float e = e1;
                h[0] = fmaf(h[0], e, du * Bv[0]);
                p[0] = h[0] * Cv[0];
#pragma unroll
                for (int n = 1; n < NS; ++n) {
                    e *= e1;
                    h[n] = fmaf(h[n], e, du * Bv[n]);
                    p[n] = h[n] * Cv[n];
                }
            } else {
#pragma unroll
                for (int n = 0; n < NS; ++n) {
                    float e = __expf(dt * Aa[n]);
                    h[n] = fmaf(h[n], e, du * Bv[n]);
                    p[n] = h[n] * Cv[n];
                }
            }
#pragma unroll
            for (int s = 8; s >= 1; s >>= 1)
#pragma unroll
                for (int n = 0; n < 8; ++n)
                    if (n < s) p[n] = p[n] + p[n + s];
            float y = fmaf(Dd, u, p[0]);

            int lg = l0 + l;
            int pos;
            if      (k == 0) pos = lg;
            else if (k == 1) pos = (lg % H_SZ) * W_SZ + (lg / H_SZ);
            else if (k == 2) pos = L_SZ - 1 - lg;
            else { int j = L_SZ - 1 - lg; pos = (j % H_SZ) * W_SZ + (j / H_SZ); }
            ypre_b[(size_t)(b * L_SZ + pos) * CIN + k * DI + d] = f2b(y);
        }
    }
}

// ---------------------------------------------------------------------------
// Fallback separate scan kernels (proven round-6 versions).
// ---------------------------------------------------------------------------
__global__ __launch_bounds__(192) void scan_passA(
        const ushort* __restrict__ dts_b, const ushort* __restrict__ xsb,
        const float* __restrict__ xdbl, const float* __restrict__ A_logs,
        float* __restrict__ Ebuf, float* __restrict__ Sbuf,
        float* __restrict__ Pbuf) {
    int blk = blockIdx.x;
    int bk = blk / NC, ch = blk % NC;
    int d = threadIdx.x, k = bk % KG;
    int l0 = ch * CL;

    __shared__ float bsh[CL][NS];
    for (int t = threadIdx.x; t < CL * NS; t += 192) {
        int l = t / NS, n = t % NS;
        bsh[l][n] = xdbl[(size_t)(bk * L_SZ + l0 + l) * XD + RR + n];
    }
    __syncthreads();

    float Aa[NS], S[NS];
    const float* ar = &A_logs[(size_t)(k * DI + d) * NS];
    bool fast = true;
#pragma unroll
    for (int n = 0; n < NS; ++n) {
        Aa[n] = -__expf(ar[n]);
        S[n] = 0.f;
        fast = fast && (fabsf(Aa[n] + (float)(n + 1)) < 1e-4f * (n + 1));
    }

    float* sp = &Sbuf[(size_t)((bk * NC + ch) * DI + d) * NS];
    if (fast) {
        float P = 1.f;
#pragma unroll
        for (int l = 0; l < CL; ++l) {
            float dt = b2f(dts_b[(size_t)(bk * L_SZ + l0 + l) * DI + d]);
            float u  = b2f(xsb [(size_t)(bk * L_SZ + l0 + l) * DI + d]);
            float du = dt * u;
            float4 b0 = *(const float4*)&bsh[l][0];
            float4 b1 = *(const float4*)&bsh[l][4];
            float4 b2 = *(const float4*)&bsh[l][8];
            float4 b3 = *(const float4*)&bsh[l][12];
            float Bv[NS] = {b0.x,b0.y,b0.z,b0.w, b1.x,b1.y,b1.z,b1.w,
                            b2.x,b2.y,b2.z,b2.w, b3.x,b3.y,b3.z,b3.w};
            float e1 = __expf(-dt);
            P *= e1;
            float e = e1;
            S[0] = fmaf(S[0], e, du * Bv[0]);
#pragma unroll
            for (int n = 1; n < NS; ++n) {
                e *= e1;
                S[n] = fmaf(S[n], e, du * Bv[n]);
            }
        }
        Pbuf[(size_t)(bk * NC + ch) * DI + d] = P;
#pragma unroll
        for (int q = 0; q < 4; ++q) {
            float4 v = {S[q*4], S[q*4+1], S[q*4+2], S[q*4+3]};
            *(float4*)&sp[q * 4] = v;
        }
    } else {
        float E[NS];
#pragma unroll
        for (int n = 0; n < NS; ++n) E[n] = 1.f;
#pragma unroll 8
        for (int l = 0; l < CL; ++l) {
            float dt = b2f(dts_b[(size_t)(bk * L_SZ + l0 + l) * DI + d]);
            float u  = b2f(xsb [(size_t)(bk * L_SZ + l0 + l) * DI + d]);
            float du = dt * u;
            float4 b0 = *(const float4*)&bsh[l][0];
            float4 b1 = *(const float4*)&bsh[l][4];
            float4 b2 = *(const float4*)&bsh[l][8];
            float4 b3 = *(const float4*)&bsh[l][12];
            float Bv[NS] = {b0.x,b0.y,b0.z,b0.w, b1.x,b1.y,b1.z,b1.w,
                            b2.x,b2.y,b2.z,b2.w, b3.x,b3.y,b3.z,b3.w};
#pragma unroll
            for (int n = 0; n < NS; ++n) {
                float e = __expf(dt * Aa[n]);
                E[n] *= e;
                S[n] = fmaf(S[n], e, du * Bv[n]);
            }
        }
        Pbuf[(size_t)(bk * NC + ch) * DI + d] = -1.f;
        float* ep = &Ebuf[(size_t)((bk * NC + ch) * DI + d) * NS];
#pragma unroll
        for (int q = 0; q < 4; ++q) {
            float4 ve = {E[q*4], E[q*4+1], E[q*4+2], E[q*4+3]};
            float4 vs = {S[q*4], S[q*4+1], S[q*4+2], S[q*4+3]};
            *(float4*)&ep[q * 4] = ve;
            *(float4*)&sp[q * 4] = vs;
        }
    }
}

__global__ __launch_bounds__(64) void scan_passB(
        const float* __restrict__ Ebuf, const float* __restrict__ Sbuf,
        const float* __restrict__ Pbuf, float* __restrict__ Hstart) {
    constexpr int P = 8;
    int t = blockIdx.x * 64 + threadIdx.x;
    int bk = t / (DI * 4);
    int dn = (t % (DI * 4)) * 4;
    int d  = dn >> 4;
    int n0 = dn & 15;
    const size_t stride = (size_t)DI * NS;
    size_t off  = (size_t)(bk * NC) * stride + dn;
    const float* pb = &Pbuf[(size_t)(bk * NC) * DI + d];

    float4 h = {0.f, 0.f, 0.f, 0.f};
    bool fastu = (pb[0] >= 0.f);

    if (fastu) {
        float  pA[P], pB[P];
        float4 sA[P], sB[P];
        size_t offL = off;
        int    cP   = 0;
#pragma unroll
        for (int j = 0; j < P; ++j) {
            pA[j] = pb[(size_t)(cP + j) * DI];
            sA[j] = *(const float4*)&Sbuf[offL + (size_t)j * stride];
        }
        offL += (size_t)P * stride; cP += P;

        for (int c = 0; c < NC; c += 2 * P) {
#pragma unroll
            for (int j = 0; j < P; ++j) {
                pB[j] = pb[(size_t)(cP + j) * DI];
                sB[j] = *(const float4*)&Sbuf[offL + (size_t)j * stride];
            }
            offL += (size_t)P * stride; cP += P;

#pragma unroll
            for (int j = 0; j < P; ++j) {
                *(float4*)&Hstart[off + (size_t)j * stride] = h;
                float Pv = pA[j];
                float P2 = Pv * Pv, P3 = P2 * Pv;
                float P4 = P2 * P2, P8 = P4 * P4;
                float base = Pv * ((n0 & 4) ? P4 : 1.f) * ((n0 & 8) ? P8 : 1.f);
                h.x = fmaf(base,      h.x, sA[j].x);
                h.y = fmaf(base * Pv, h.y, sA[j].y);
                h.z = fmaf(base * P2, h.z, sA[j].z);
                h.w = fmaf(base * P3, h.w, sA[j].w);
            }
            off += (size_t)P * stride;

            if (c + 2 * P < NC) {
#pragma unroll
                for (int j = 0; j < P; ++j) {
                    pA[j] = pb[(size_t)(cP + j) * DI];
                    sA[j] = *(const float4*)&Sbuf[offL + (size_t)j * stride];
                }
            }
            offL += (size_t)P * stride; cP += P;

#pragma unroll
            for (int j = 0; j < P; ++j) {
                *(float4*)&Hstart[off + (size_t)j * stride] = h;
                float Pv = pB[j];
                float P2 = Pv * Pv, P3 = P2 * Pv;
                float P4 = P2 * P2, P8 = P4 * P4;
                float base = Pv * ((n0 & 4) ? P4 : 1.f) * ((n0 & 8) ? P8 : 1.f);
                h.x = fmaf(base,      h.x, sB[j].x);
                h.y = fmaf(base * Pv, h.y, sB[j].y);
                h.z = fmaf(base * P2, h.z, sB[j].z);
                h.w = fmaf(base * P3, h.w, sB[j].w);
            }
            off += (size_t)P * stride;
        }
    } else {
        float4 eA[P], sA[P], eB[P], sB[P];
        size_t offL = off;
#pragma unroll
        for (int j = 0; j < P; ++j) {
            eA[j] = *(const float4*)&Ebuf[offL + (size_t)j * stride];
            sA[j] = *(const float4*)&Sbuf[offL + (size_t)j * stride];
        }
        offL += (size_t)P * stride;

        for (int c = 0; c < NC; c += 2 * P) {
#pragma unroll
            for (int j = 0; j < P; ++j) {
                eB[j] = *(const float4*)&Ebuf[offL + (size_t)j * stride];
                sB[j] = *(const float4*)&Sbuf[offL + (size_t)j * stride];
            }
            offL += (size_t)P * stride;

#pragma unroll
            for (int j = 0; j < P; ++j) {
                *(float4*)&Hstart[off + (size_t)j * stride] = h;
                h.x = fmaf(eA[j].x, h.x, sA[j].x);
                h.y = fmaf(eA[j].y, h.y, sA[j].y);
                h.z = fmaf(eA[j].z, h.z, sA[j].z);
                h.w = fmaf(eA[j].w, h.w, sA[j].w);
            }
            off += (size_t)P * stride;

            if (c + 2 * P < NC) {
#pragma unroll
                for (int j = 0; j < P; ++j) {
                    eA[j] = *(const float4*)&Ebuf[offL + (size_t)j * stride];
                    sA[j] = *(const float4*)&Sbuf[offL + (size_t)j * stride];
                }
            }
            offL += (size_t)P * stride;

#pragma unroll
            for (int j = 0; j < P; ++j) {
                *(float4*)&Hstart[off + (size_t)j * stride] = h;
                h.x = fmaf(eB[j].x, h.x, sB[j].x);
                h.y = fmaf(eB[j].y, h.y, sB[j].y);
                h.z = fmaf(eB[j].z, h.z, sB[j].z);
                h.w = fmaf(eB[j].w, h.w, sB[j].w);
            }
            off += (size_t)P * stride;
        }
    }
}

__global__ __launch_bounds__(192) void scan_passC(
        const ushort* __restrict__ dts_b, const ushort* __restrict__ xsb,
        const float* __restrict__ xdbl, const float* __restrict__ A_logs,
        const float* __restrict__ Hstart, const float* __restrict__ Ds,
        ushort* __restrict__ ypre_b) {
    int blk = blockIdx.x;
    int bk = blk / NC, ch = blk % NC;
    int d = threadIdx.x, k = bk % KG, b = bk / KG;
    int l0 = ch * CL;

    __shared__ float bsh[CL][NS];
    __shared__ float csh[CL][NS];
    for (int t = threadIdx.x; t < CL * NS; t += 192) {
        int l = t / NS, n = t % NS;
        const float* row = &xdbl[(size_t)(bk * L_SZ + l0 + l) * XD];
        bsh[l][n] = row[RR + n];
        csh[l][n] = row[RR + NS + n];
    }
    __syncthreads();

    float Aa[NS], h[NS];
    const float* ar = &A_logs[(size_t)(k * DI + d) * NS];
    const float* hp = &Hstart[(size_t)((bk * NC + ch) * DI + d) * NS];
    bool fast = true;
#pragma unroll
    for (int n = 0; n < NS; ++n) {
        Aa[n] = -__expf(ar[n]);
        h[n] = hp[n];
        fast = fast && (fabsf(Aa[n] + (float)(n + 1)) < 1e-4f * (n + 1));
    }
    float Dd = Ds[k * DI + d];

#pragma unroll 8
    for (int l = 0; l < CL; ++l) {
        float dt = b2f(dts_b[(size_t)(bk * L_SZ + l0 + l) * DI + d]);
        float u  = b2f(xsb [(size_t)(bk * L_SZ + l0 + l) * DI + d]);
        float du = dt * u;
        float4 b0 = *(const float4*)&bsh[l][0];
        float4 b1 = *(const float4*)&bsh[l][4];
        float4 b2 = *(const float4*)&bsh[l][8];
        float4 b3 = *(const float4*)&bsh[l][12];
        float Bv[NS] = {b0.x,b0.y,b0.z,b0.w, b1.x,b1.y,b1.z,b1.w,
                        b2.x,b2.y,b2.z,b2.w, b3.x,b3.y,b3.z,b3.w};
        float4 c0 = *(const float4*)&csh[l][0];
        float4 c1 = *(const float4*)&csh[l][4];
        float4 c2 = *(const float4*)&csh[l][8];
        float4 c3 = *(const float4*)&csh[l][12];
        float Cv[NS] = {c0.x,c0.y,c0.z,c0.w, c1.x,c1.y,c1.z,c1.w,
                        c2.x,c2.y,c2.z,c2.w, c3.x,c3.y,c3.z,c3.w};
        float p[NS];
        if (fast) {
            float e1 = __expf(-dt);
            float e = e1;
            h[0] = fmaf(h[0], e, du * Bv[0]);
            p[0] = h[0] * Cv[0];
#pragma unroll
            for (int n = 1; n < NS; ++n) {
                e *= e1;
                h[n] = fmaf(h[n], e, du * Bv[n]);
                p[n] = h[n] * Cv[n];
            }
        } else {
#pragma unroll
            for (int n = 0; n < NS; ++n) {
                float e = __expf(dt * Aa[n]);
                h[n] = fmaf(h[n], e, du * Bv[n]);
                p[n] = h[n] * Cv[n];
            }
        }
#pragma unroll
        for (int s = 8; s >= 1; s >>= 1)
#pragma unroll
            for (int n = 0; n < 8; ++n)
                if (n < s) p[n] = p[n] + p[n + s];
        float y = fmaf(Dd, u, p[0]);

        int lg = l0 + l;
        int pos;
        if      (k == 0) pos = lg;
        else if (k == 1) pos = (lg % H_SZ) * W_SZ + (lg / H_SZ);
        else if (k == 2) pos = L_SZ - 1 - lg;
        else { int j = L_SZ - 1 - lg; pos = (j % H_SZ) * W_SZ + (j / H_SZ); }
        ypre_b[(size_t)(b * L_SZ + pos) * CIN + k * DI + d] = f2b(y);
    }
}

// ---------------------------------------------------------------------------
// LayerNorm over CIN=768; bf16 in, bf16 out (stats in fp32).
// ---------------------------------------------------------------------------
__global__ __launch_bounds__(256) void layernorm_bf16(
        const ushort* __restrict__ y, ushort* __restrict__ yb,
        const float* __restrict__ w, const float* __restrict__ bg) {
    int wave = threadIdx.x >> 6, lane = threadIdx.x & 63;
    int tok = blockIdx.x * 4 + wave;
    const ushort* row = &y[(size_t)tok * CIN];
    ushort* rowo = &yb[(size_t)tok * CIN];
    float v[12];
    float s = 0.f;
#pragma unroll
    for (int i = 0; i < 12; ++i) { v[i] = b2f(row[lane + i * 64]); s += v[i]; }
#pragma unroll
    for (int off = 32; off >= 1; off >>= 1) s += __shfl_xor(s, off, 64);
    float mu = s * (1.f / CIN);
    float s2 = 0.f;
#pragma unroll
    for (int i = 0; i < 12; ++i) { float t = v[i] - mu; s2 += t * t; }
#pragma unroll
    for (int off = 32; off >= 1; off >>= 1) s2 += __shfl_xor(s2, off, 64);
    float rstd = rsqrtf(s2 * (1.f / CIN) + 1e-5f);
#pragma unroll
    for (int i = 0; i < 12; ++i)
        rowo[lane + i * 64] =
            f2b((v[i] - mu) * rstd * w[lane + i * 64] + bg[lane + i * 64]);
}

// ---------------------------------------------------------------------------
extern "C" void kernel_launch(void* const* d_in, const int* in_sizes, int n_in,
                              void* d_out, int out_size, void* d_ws, size_t ws_size,
                              hipStream_t stream) {
    const float* x    = (const float*)d_in[0];
    const float* inw  = (const float*)d_in[1];
    const float* cw   = (const float*)d_in[2];
    const float* cb   = (const float*)d_in[3];
    const float* xpw  = (const float*)d_in[4];
    const float* dtw  = (const float*)d_in[5];
    const float* dtb  = (const float*)d_in[6];
    const float* alog = (const float*)d_in[7];
    const float* Dsp  = (const float*)d_in[8];
    const float* lnw  = (const float*)d_in[9];
    const float* lnb  = (const float*)d_in[10];
    const float* outw = (const float*)d_in[11];
    float* out = (float*)d_out;

    float* ws = (float*)d_ws;
    const size_t SZ_BIG = (size_t)MTOK * CIN;            // 3,538,944
    const size_t SCAN_SL = (size_t)8 * NC * DI * NS;     // 3,538,944 (CL=16)
    float* xz    = ws;
    float* xsbf  = xz  + SZ_BIG;
    float* dts   = xsbf + SZ_BIG / 2;
    float* xdbl  = dts + SZ_BIG;
    float* Ebuf  = xdbl + (size_t)8 * L_SZ * XD;
    float* Sbuf  = Ebuf + SCAN_SL;
    float* Hst   = Sbuf + SCAN_SL;
    float* Pbuf  = Hst + SCAN_SL;                        // 8*NC*DI fp32
    uint*  bar   = (uint*)(Pbuf + (size_t)8 * NC * DI);  // 2 uints
    // overlays (strictly sequential producer/consumer):
    ushort* xzb    = (ushort*)xz;
    ushort* xsb    = (ushort*)xsbf;
    ushort* dtsb   = (ushort*)dts;
    ushort* ypre_b = (ushort*)xz;
    ushort* ynrm_b = (ushort*)dts;

    // 1. in-proj GEMM
    gemm_tn64<128, false, true><<<dim3(CIN / 64, MTOK / 128), 256, 0, stream>>>(
        x, inw, xzb, MTOK, CIN, 384);
    // 2. depthwise conv + SiLU + scatter
    conv_silu_scatter<<<(B_SZ * H_SZ * W_SZ * 96) / 256, 256, 0, stream>>>(xzb, cw, cb, xsb);
    // 3. fused MFMA x-projection + dt-projection
    xproj_dt_mfma<<<dim3(L_SZ / 32, 8), 384, 0, stream>>>(xsb, xpw, dtw, dtb, xdbl, dtsb);

    // 4. scan: fused single-kernel path if all blocks fit co-resident
    int maxb = 0;
    hipError_t oe = hipOccupancyMaxActiveBlocksPerMultiprocessor(
        &maxb, scan_fused, 192, 0);
    if (oe == hipSuccess && maxb * 256 >= 8 * NC) {
        hipMemsetAsync(bar, 0, 2 * sizeof(uint), stream);
        scan_fused<<<8 * NC, 192, 0, stream>>>(
            dtsb, xsb, xdbl, alog, Ebuf, Sbuf, Pbuf, Hst, Dsp, ypre_b, bar);
    } else {
        scan_passA<<<8 * NC, 192, 0, stream>>>(dtsb, xsb, xdbl, alog, Ebuf, Sbuf, Pbuf);
        scan_passB<<<(8 * DI * 4) / 64, 64, 0, stream>>>(Ebuf, Sbuf, Pbuf, Hst);
        scan_passC<<<8 * NC, 192, 0, stream>>>(dtsb, xsb, xdbl, alog, Hst, Dsp, ypre_b);
    }
    // 5. LayerNorm
    layernorm_bf16<<<MTOK / 4, 256, 0, stream>>>(ypre_b, ynrm_b, lnw, lnb);
    // 6. out-proj GEMM
    gemm_tn64<64, true, false><<<dim3(384 / 64, MTOK / 64), 256, 0, stream>>>(
        ynrm_b, outw, out, MTOK, 384, CIN);
}